// Round 1
// baseline (700.826 us; speedup 1.0000x reference)
//
#include <hip/hip_runtime.h>

#define T_TOTAL 8192
#define DIMK 1024
#define DG 256
#define NE 16
#define NN 17
#define TB 16

// ws layout (floats)
#define EXP_OFF  0        // exp [16][256]
#define S_OFF    4096     // S [17][256]
#define AVEC_OFF 8448     // a [17]
#define AMAT_OFF 8465     // A [17*17]

// ---------- kernel 1: exp = relu(X @ W_struct), one block per expert ----------
__global__ __launch_bounds__(256) void k_exp(const float* __restrict__ X,
                                             const float* __restrict__ Ws,
                                             float* __restrict__ ws) {
    const int e = blockIdx.x, d = threadIdx.x;
    float acc = 0.f;
    for (int k = 0; k < DIMK; ++k)
        acc = fmaf(X[e * DIMK + k], Ws[k * DG + d], acc);
    ws[EXP_OFF + e * DG + d] = fmaxf(acc, 0.f);
}

// ---------- kernel 2: normalized adjacency + shared layer-1 term ----------
__global__ __launch_bounds__(256) void k_setup(const float* __restrict__ W1,
                                               const float* __restrict__ adj,
                                               float* __restrict__ ws) {
    const int d = threadIdx.x;
    __shared__ float exp_s[NE][DG];
    __shared__ float An[NN][NN];
    __shared__ float dinv[NN];

    for (int e = 0; e < NE; ++e) exp_s[e][d] = ws[EXP_OFF + e * DG + d];

    if (d < NN) {
        float deg = 0.f;
        for (int m = 0; m < NN; ++m) deg += adj[d * NN + m];
        dinv[d] = (deg > 0.f) ? (1.0f / sqrtf(deg)) : 0.f;
    }
    __syncthreads();
    for (int i = d; i < NN * NN; i += 256)
        An[i / NN][i % NN] = adj[i] * dinv[i / NN] * dinv[i % NN];
    __syncthreads();

    // expW1[e][d] in registers
    float ew[NE];
#pragma unroll
    for (int e = 0; e < NE; ++e) ew[e] = 0.f;
    for (int m = 0; m < DG; ++m) {
        float w = W1[m * DG + d];
#pragma unroll
        for (int e = 0; e < NE; ++e) ew[e] = fmaf(exp_s[e][m], w, ew[e]);
    }
    // S[n][d] = sum_e An[n][e] * expW1[e][d]
    for (int n = 0; n < NN; ++n) {
        float s = 0.f;
#pragma unroll
        for (int e = 0; e < NE; ++e) s = fmaf(An[n][e], ew[e], s);
        ws[S_OFF + n * DG + d] = s;
    }
    if (d < NN) ws[AVEC_OFF + d] = An[d][NE];
    for (int i = d; i < NN * NN; i += 256) ws[AMAT_OFF + i] = An[i / NN][i % NN];
}

// ---------- kernel 3: fused per-token pipeline ----------
__global__ __launch_bounds__(256) void k_main(const float* __restrict__ x,
                                              const float* __restrict__ Wm,
                                              const float* __restrict__ W1,
                                              const float* __restrict__ W2,
                                              const float* __restrict__ Wp,
                                              const float* __restrict__ ws,
                                              float* __restrict__ out) {
    const int d = threadIdx.x;
    const int t0 = blockIdx.x * TB;

    __shared__ float S_s[NN][DG];      // 17408 B
    __shared__ float a_s[NN];
    __shared__ float A_s[NN][NN];
    __shared__ float xk[TB][128];      // 8192 B
    __shared__ float hg[TB][DG];       // 16384 B (h tile, then g tile)
    __shared__ float y1[NN][DG];       // 17408 B
    __shared__ float red[4][NE];

    for (int n = 0; n < NN; ++n) S_s[n][d] = ws[S_OFF + n * DG + d];
    if (d < NN) a_s[d] = ws[AVEC_OFF + d];
    for (int i = d; i < NN * NN; i += 256) A_s[i / NN][i % NN] = ws[AMAT_OFF + i];

    // ---- phase 1: h[t][d] = relu(x[t] . Wm[:,d]) ----
    float acc[TB];
#pragma unroll
    for (int t = 0; t < TB; ++t) acc[t] = 0.f;
    for (int kc = 0; kc < DIMK; kc += 128) {
        __syncthreads();
#pragma unroll
        for (int i = 0; i < 2; ++i) {
            int f = i * 256 + d;          // 0..511 float4s
            int t = f >> 5, k4 = f & 31;
            float4 v = *reinterpret_cast<const float4*>(
                &x[(size_t)(t0 + t) * DIMK + kc + k4 * 4]);
            *reinterpret_cast<float4*>(&xk[t][k4 * 4]) = v;
        }
        __syncthreads();
        for (int k = 0; k < 128; ++k) {
            float w = Wm[(size_t)(kc + k) * DG + d];
#pragma unroll
            for (int t = 0; t < TB; ++t) acc[t] = fmaf(xk[t][k], w, acc[t]);
        }
    }
    __syncthreads();
#pragma unroll
    for (int t = 0; t < TB; ++t) hg[t][d] = fmaxf(acc[t], 0.f);
    __syncthreads();

    // ---- phase 2: g[t][d] = h[t] . W1[:,d]  (no relu here) ----
    float gac[TB];
#pragma unroll
    for (int t = 0; t < TB; ++t) gac[t] = 0.f;
    for (int m = 0; m < DG; ++m) {
        float w = W1[m * DG + d];
#pragma unroll
        for (int t = 0; t < TB; ++t) gac[t] = fmaf(hg[t][m], w, gac[t]);
    }
    __syncthreads();
#pragma unroll
    for (int t = 0; t < TB; ++t) hg[t][d] = gac[t];   // own column, no race

    const float wp = Wp[d];
    const int wave = d >> 6, lane = d & 63;

    // ---- phase 3: per token — layer1 combine, layer2 GEMM, aggregate, proj ----
    for (int t = 0; t < TB; ++t) {
        __syncthreads();                  // guards y1 & red reuse
        float g = hg[t][d];
#pragma unroll
        for (int n = 0; n < NN; ++n)
            y1[n][d] = fmaxf(fmaf(a_s[n], g, S_s[n][d]), 0.f);
        __syncthreads();

        float z[NN];
#pragma unroll
        for (int n = 0; n < NN; ++n) z[n] = 0.f;
        for (int k = 0; k < DG; k += 4) {
            float w0 = W2[(k + 0) * DG + d];
            float w1 = W2[(k + 1) * DG + d];
            float w2 = W2[(k + 2) * DG + d];
            float w3 = W2[(k + 3) * DG + d];
#pragma unroll
            for (int n = 0; n < NN; ++n) {
                float4 yv = *reinterpret_cast<const float4*>(&y1[n][k]);
                z[n] = fmaf(yv.x, w0, z[n]);
                z[n] = fmaf(yv.y, w1, z[n]);
                z[n] = fmaf(yv.z, w2, z[n]);
                z[n] = fmaf(yv.w, w3, z[n]);
            }
        }

        // y2[n][d] = relu(sum_m A[n][m] * z[m]); score[n] = sum_d y2[n][d]*wp
#pragma unroll
        for (int n = 0; n < NE; ++n) {
            float y2 = 0.f;
#pragma unroll
            for (int m = 0; m < NN; ++m) y2 = fmaf(A_s[n][m], z[m], y2);
            y2 = fmaxf(y2, 0.f);
            float v = y2 * wp;
#pragma unroll
            for (int off = 32; off > 0; off >>= 1)
                v += __shfl_down(v, off, 64);
            if (lane == 0) red[wave][n] = v;
        }
        __syncthreads();
        if (d < NE)
            out[(size_t)(t0 + t) * NE + d] =
                red[0][d] + red[1][d] + red[2][d] + red[3][d];
    }
}

extern "C" void kernel_launch(void* const* d_in, const int* in_sizes, int n_in,
                              void* d_out, int out_size, void* d_ws, size_t ws_size,
                              hipStream_t stream) {
    const float* x   = (const float*)d_in[0];
    const float* X   = (const float*)d_in[1];
    const float* Wm  = (const float*)d_in[2];
    const float* Wst = (const float*)d_in[3];
    const float* Wc  = (const float*)d_in[4];
    const float* Wp  = (const float*)d_in[5];
    const float* adj = (const float*)d_in[6];
    float* out = (float*)d_out;
    float* ws  = (float*)d_ws;
    const float* W1 = Wc;
    const float* W2 = Wc + DG * DG;

    k_exp<<<NE, 256, 0, stream>>>(X, Wst, ws);
    k_setup<<<1, 256, 0, stream>>>(W1, adj, ws);
    k_main<<<T_TOTAL / TB, 256, 0, stream>>>(x, Wm, W1, W2, Wp, ws, out);
}

// Round 2
// 198.478 us; speedup vs baseline: 3.5310x; 3.5310x over previous
//
#include <hip/hip_runtime.h>

typedef __attribute__((ext_vector_type(4))) float f32x4;
typedef __attribute__((ext_vector_type(8))) short s16x8;

#define MFMA16(a, b, c) __builtin_amdgcn_mfma_f32_16x16x32_bf16(a, b, c, 0, 0, 0)

#define DG 256
#define NE 16
#define NN 17
#define TB 32
#define NTOK 8192

// ws float offsets (small data)
#define WS_S    0        // S [17][256]
#define WS_A    4352     // a [17]
#define WS_AD   4376     // A dense [17*17]
#define WS_EXP  4672     // exp [16][256]
#define WS_EW   8768     // exp@W1 [16][256]
// ws byte offsets (pre-swizzled bf16 hi/lo weight fragments)
#define FB_WMH  65536
#define FB_WML  589824
#define FB_W1H  1114112
#define FB_W1L  1245184
#define FB_W2H  1376256
#define FB_W2L  1507328
#define WS_NEED 1638400

__device__ __forceinline__ ushort bf16h(float f) {
    union { float f; uint u; } c; c.f = f;
    return (ushort)((c.u + 0x7fffu + ((c.u >> 16) & 1u)) >> 16);  // RNE
}
__device__ __forceinline__ float bf16tof(ushort h) {
    union { uint u; float f; } c; c.u = (uint)h << 16;
    return c.f;
}
__device__ __forceinline__ void cvt_hilo(f32x4 a, f32x4 b, s16x8& hi, s16x8& lo) {
#pragma unroll
    for (int i = 0; i < 4; ++i) {
        const ushort h = bf16h(a[i]);
        hi[i] = (short)h;
        lo[i] = (short)bf16h(a[i] - bf16tof(h));
    }
#pragma unroll
    for (int i = 0; i < 4; ++i) {
        const ushort h = bf16h(b[i]);
        hi[4 + i] = (short)h;
        lo[4 + i] = (short)bf16h(b[i] - bf16tof(h));
    }
}

// B-operand fragment: b[i] = W[ks*32 + 8*(lane>>4) + i][nt*16 + (lane&15)]
template<bool SWZ>
__device__ __forceinline__ void loadB(const ushort* __restrict__ H,
                                      const ushort* __restrict__ L,
                                      const float* __restrict__ Wf,
                                      int KST, int nt, int ks, int lane,
                                      s16x8& bh, s16x8& bl) {
    if (SWZ) {
        const size_t off = ((size_t)(nt * KST + ks) * 64 + lane) * 8;
        bh = *(const s16x8*)(H + off);
        bl = *(const s16x8*)(L + off);
    } else {
        const int k0 = ks * 32 + ((lane >> 4) << 3);
        const int col = nt * 16 + (lane & 15);
        const float* p = Wf + (size_t)k0 * DG + col;
        f32x4 v0, v1;
#pragma unroll
        for (int i = 0; i < 4; ++i) v0[i] = p[(size_t)i * DG];
#pragma unroll
        for (int i = 0; i < 4; ++i) v1[i] = p[(size_t)(4 + i) * DG];
        cvt_hilo(v0, v1, bh, bl);
    }
}

// ---------------- setup kernels ----------------
__global__ __launch_bounds__(256) void k_exp(const float* __restrict__ X,
                                             const float* __restrict__ Wst,
                                             float* __restrict__ ws) {
    const int e = blockIdx.x, d = threadIdx.x;
    float acc = 0.f;
    for (int k = 0; k < 1024; ++k)
        acc = fmaf(X[e * 1024 + k], Wst[k * DG + d], acc);
    ws[WS_EXP + e * DG + d] = fmaxf(acc, 0.f);
}

__global__ __launch_bounds__(256) void k_ew(float* __restrict__ ws,
                                            const float* __restrict__ W1) {
    const int e = blockIdx.x, d = threadIdx.x;
    float acc = 0.f;
    for (int m = 0; m < DG; ++m)
        acc = fmaf(ws[WS_EXP + e * DG + m], W1[m * DG + d], acc);
    ws[WS_EW + e * DG + d] = acc;
}

__global__ __launch_bounds__(256) void k_S(const float* __restrict__ adj,
                                           float* __restrict__ ws) {
    __shared__ float dinv[NN];
    __shared__ float row[NN];
    const int tid = threadIdx.x, b = blockIdx.x;
    if (tid < NN) {
        float deg = 0.f;
        for (int m = 0; m < NN; ++m) deg += adj[tid * NN + m];
        dinv[tid] = 1.0f / sqrtf(deg);
    }
    __syncthreads();
    if (b < NN) {
        if (tid < NN) row[tid] = adj[b * NN + tid] * dinv[b] * dinv[tid];
        __syncthreads();
        float s = 0.f;
        for (int e = 0; e < NE; ++e) s = fmaf(row[e], ws[WS_EW + e * DG + tid], s);
        ws[WS_S + b * DG + tid] = s;
    } else {
        if (tid < NN) ws[WS_A + tid] = adj[tid * NN + NE] * dinv[tid] * dinv[NE];
        for (int i = tid; i < NN * NN; i += 256)
            ws[WS_AD + i] = adj[i] * dinv[i / NN] * dinv[i % NN];
    }
}

__global__ __launch_bounds__(256) void k_swz(const float* __restrict__ Wm,
                                             const float* __restrict__ W1,
                                             const float* __restrict__ W2,
                                             float* __restrict__ ws) {
    const int gid = blockIdx.x * 256 + threadIdx.x;
    const float* W; ushort* H; ushort* L; int local, KST;
    char* base = (char*)ws;
    if (gid < 262144)      { W = Wm; KST = 32; local = gid;          H = (ushort*)(base + FB_WMH); L = (ushort*)(base + FB_WML); }
    else if (gid < 327680) { W = W1; KST = 8;  local = gid - 262144; H = (ushort*)(base + FB_W1H); L = (ushort*)(base + FB_W1L); }
    else                   { W = W2; KST = 8;  local = gid - 327680; H = (ushort*)(base + FB_W2H); L = (ushort*)(base + FB_W2L); }
    const int i = local & 7, l = (local >> 3) & 63, t = local >> 9;
    const int ks = t % KST, nt = t / KST;
    const int k = ks * 32 + ((l >> 4) << 3) + i;
    const int col = nt * 16 + (l & 15);
    const float wv = W[(size_t)k * DG + col];
    const ushort h = bf16h(wv);
    H[local] = h;
    L[local] = bf16h(wv - bf16tof(h));
}

// ---------------- fused main kernel ----------------
template<bool SWZ>
__global__ __launch_bounds__(512, 2) void k_main(
        const float* __restrict__ x,
        const float* __restrict__ Wm,
        const float* __restrict__ W1,
        const float* __restrict__ W2,
        const float* __restrict__ Wp,
        const float* __restrict__ ws,
        float* __restrict__ out) {
    const int tid = threadIdx.x;
    const int lane = tid & 63, w = tid >> 6;
    const int r16 = lane & 15, g4 = lane >> 4;
    const int nt0 = 2 * w, nt1 = nt0 + 1;
    const size_t t0 = (size_t)blockIdx.x * TB;

    __shared__ float S_s[NN][260];
    __shared__ float g_s[TB][260];
    __shared__ alignas(16) union { float h[TB][260]; ushort frag[2][NN * 64 * 8]; } U;
    __shared__ float part[8][16][NE];
    __shared__ float a_l[NN];
    __shared__ float Ad_l[NN * NN];

    for (int j = tid; j < NN * DG; j += 512) S_s[j >> 8][j & 255] = ws[WS_S + j];
    if (tid < NN) a_l[tid] = ws[WS_A + tid];
    for (int j = tid; j < NN * NN; j += 512) Ad_l[j] = ws[WS_AD + j];

    const char* base = (const char*)ws;
    const ushort* WmH = (const ushort*)(base + FB_WMH);
    const ushort* WmL = (const ushort*)(base + FB_WML);
    const ushort* W1H = (const ushort*)(base + FB_W1H);
    const ushort* W1L = (const ushort*)(base + FB_W1L);
    const ushort* W2H = (const ushort*)(base + FB_W2H);
    const ushort* W2L = (const ushort*)(base + FB_W2L);

    // ---- phase A: h = relu(x @ Wm), M=32 K=1024 ----
    f32x4 hacc[2][2];
#pragma unroll
    for (int mt = 0; mt < 2; ++mt)
#pragma unroll
        for (int j = 0; j < 2; ++j) hacc[mt][j] = (f32x4){0.f, 0.f, 0.f, 0.f};

    for (int ks = 0; ks < 32; ++ks) {
        s16x8 ah[2], aL[2];
#pragma unroll
        for (int mt = 0; mt < 2; ++mt) {
            const float* px = x + (t0 + mt * 16 + r16) * 1024 + ks * 32 + g4 * 8;
            cvt_hilo(*(const f32x4*)px, *(const f32x4*)(px + 4), ah[mt], aL[mt]);
        }
        s16x8 bh[2], bl[2];
        loadB<SWZ>(WmH, WmL, Wm, 32, nt0, ks, lane, bh[0], bl[0]);
        loadB<SWZ>(WmH, WmL, Wm, 32, nt1, ks, lane, bh[1], bl[1]);
#pragma unroll
        for (int mt = 0; mt < 2; ++mt)
#pragma unroll
            for (int j = 0; j < 2; ++j) {
                hacc[mt][j] = MFMA16(ah[mt], bh[j], hacc[mt][j]);
                hacc[mt][j] = MFMA16(aL[mt], bh[j], hacc[mt][j]);
                hacc[mt][j] = MFMA16(ah[mt], bl[j], hacc[mt][j]);
            }
    }
#pragma unroll
    for (int mt = 0; mt < 2; ++mt)
#pragma unroll
        for (int j = 0; j < 2; ++j)
#pragma unroll
            for (int r = 0; r < 4; ++r)
                U.h[mt * 16 + g4 * 4 + r][(nt0 + j) * 16 + r16] = fmaxf(hacc[mt][j][r], 0.f);
    __syncthreads();

    // ---- phase B: g = h @ W1 (no relu), K=256 ----
    f32x4 gacc[2][2];
#pragma unroll
    for (int mt = 0; mt < 2; ++mt)
#pragma unroll
        for (int j = 0; j < 2; ++j) gacc[mt][j] = (f32x4){0.f, 0.f, 0.f, 0.f};

    for (int ks = 0; ks < 8; ++ks) {
        s16x8 ah[2], aL[2];
#pragma unroll
        for (int mt = 0; mt < 2; ++mt) {
            const float* ph = &U.h[mt * 16 + r16][ks * 32 + g4 * 8];
            cvt_hilo(*(const f32x4*)ph, *(const f32x4*)(ph + 4), ah[mt], aL[mt]);
        }
        s16x8 bh[2], bl[2];
        loadB<SWZ>(W1H, W1L, W1, 8, nt0, ks, lane, bh[0], bl[0]);
        loadB<SWZ>(W1H, W1L, W1, 8, nt1, ks, lane, bh[1], bl[1]);
#pragma unroll
        for (int mt = 0; mt < 2; ++mt)
#pragma unroll
            for (int j = 0; j < 2; ++j) {
                gacc[mt][j] = MFMA16(ah[mt], bh[j], gacc[mt][j]);
                gacc[mt][j] = MFMA16(aL[mt], bh[j], gacc[mt][j]);
                gacc[mt][j] = MFMA16(ah[mt], bl[j], gacc[mt][j]);
            }
    }
#pragma unroll
    for (int mt = 0; mt < 2; ++mt)
#pragma unroll
        for (int j = 0; j < 2; ++j)
#pragma unroll
            for (int r = 0; r < 4; ++r)
                g_s[mt * 16 + g4 * 4 + r][(nt0 + j) * 16 + r16] = gacc[mt][j][r];
    __syncthreads();

    const float wp0 = Wp[nt0 * 16 + r16], wp1 = Wp[nt1 * 16 + r16];

    // ---- phases C/D/E per 16-token sub-batch; M-tile n = 16 tokens of node n ----
    for (int sb = 0; sb < 2; ++sb) {
        f32x4 acc[NN][2];
#pragma unroll
        for (int n = 0; n < NN; ++n) {
            acc[n][0] = (f32x4){0.f, 0.f, 0.f, 0.f};
            acc[n][1] = (f32x4){0.f, 0.f, 0.f, 0.f};
        }
        for (int ks = 0; ks < 8; ++ks) {
            __syncthreads();
            // build y1 fragments (hi/lo bf16) into LDS
            for (int p = tid; p < NN * 256; p += 512) {
                const int n = p >> 8, rem = p & 255;
                const int l = rem >> 2, ip = rem & 3;
                const int k = ks * 32 + ((l >> 4) << 3) + ip * 2;
                const int row = sb * 16 + (l & 15);
                const float an = a_l[n];
                const float y0 = fmaxf(fmaf(an, g_s[row][k],     S_s[n][k]),     0.f);
                const float y1v = fmaxf(fmaf(an, g_s[row][k + 1], S_s[n][k + 1]), 0.f);
                const ushort h0 = bf16h(y0), h1 = bf16h(y1v);
                const ushort l0 = bf16h(y0 - bf16tof(h0)), l1 = bf16h(y1v - bf16tof(h1));
                ((uint*)U.frag[0])[p] = ((uint)h1 << 16) | h0;
                ((uint*)U.frag[1])[p] = ((uint)l1 << 16) | l0;
            }
            __syncthreads();
            // consume: z[node][tok][col] accumulation
            s16x8 bh0, bl0, bh1, bl1;
            loadB<SWZ>(W2H, W2L, W2, 8, nt0, ks, lane, bh0, bl0);
            loadB<SWZ>(W2H, W2L, W2, 8, nt1, ks, lane, bh1, bl1);
#pragma unroll
            for (int n = 0; n < NN; ++n) {
                const s16x8 ah = *(const s16x8*)&U.frag[0][(n * 64 + lane) * 8];
                const s16x8 aL = *(const s16x8*)&U.frag[1][(n * 64 + lane) * 8];
                acc[n][0] = MFMA16(ah, bh0, acc[n][0]);
                acc[n][0] = MFMA16(aL, bh0, acc[n][0]);
                acc[n][0] = MFMA16(ah, bl0, acc[n][0]);
                acc[n][1] = MFMA16(ah, bh1, acc[n][1]);
                acc[n][1] = MFMA16(aL, bh1, acc[n][1]);
                acc[n][1] = MFMA16(ah, bl1, acc[n][1]);
            }
        }
        // ---- phase E: y2 = relu(A @ z); score = y2 . Wp ----
        for (int e = 0; e < NE; ++e) {
            f32x4 z0 = (f32x4){0.f, 0.f, 0.f, 0.f}, z1 = (f32x4){0.f, 0.f, 0.f, 0.f};
#pragma unroll
            for (int n = 0; n < NN; ++n) {
                const float av = Ad_l[e * NN + n];
                if (av != 0.f) {   // uniform branch; A is sparse
#pragma unroll
                    for (int r = 0; r < 4; ++r) {
                        z0[r] = fmaf(av, acc[n][0][r], z0[r]);
                        z1[r] = fmaf(av, acc[n][1][r], z1[r]);
                    }
                }
            }
            float v[4];
#pragma unroll
            for (int r = 0; r < 4; ++r)
                v[r] = fmaxf(z0[r], 0.f) * wp0 + fmaxf(z1[r], 0.f) * wp1;
#pragma unroll
            for (int off = 1; off < 16; off <<= 1)
#pragma unroll
                for (int r = 0; r < 4; ++r) v[r] += __shfl_xor(v[r], off, 64);
            if (r16 == 0)
#pragma unroll
                for (int r = 0; r < 4; ++r) part[w][g4 * 4 + r][e] = v[r];
        }
        __syncthreads();
        if (tid < 256) {
            const int t = tid >> 4, e = tid & 15;
            float s = 0.f;
#pragma unroll
            for (int q = 0; q < 8; ++q) s += part[q][t][e];
            out[(t0 + sb * 16 + t) * NE + e] = s;
        }
    }
}

extern "C" void kernel_launch(void* const* d_in, const int* in_sizes, int n_in,
                              void* d_out, int out_size, void* d_ws, size_t ws_size,
                              hipStream_t stream) {
    const float* x   = (const float*)d_in[0];
    const float* X   = (const float*)d_in[1];
    const float* Wm  = (const float*)d_in[2];
    const float* Wst = (const float*)d_in[3];
    const float* Wc  = (const float*)d_in[4];
    const float* Wp  = (const float*)d_in[5];
    const float* adj = (const float*)d_in[6];
    float* out = (float*)d_out;
    float* ws  = (float*)d_ws;
    const float* W1 = Wc;
    const float* W2 = Wc + DG * DG;

    k_exp<<<NE, 256, 0, stream>>>(X, Wst, ws);
    k_ew<<<NE, 256, 0, stream>>>(ws, W1);
    k_S<<<NN + 1, 256, 0, stream>>>(adj, ws);

    if (ws_size >= (size_t)WS_NEED) {
        k_swz<<<1536, 256, 0, stream>>>(Wm, W1, W2, ws);
        k_main<true><<<256, 512, 0, stream>>>(x, Wm, W1, W2, Wp, ws, out);
    } else {
        k_main<false><<<256, 512, 0, stream>>>(x, Wm, W1, W2, Wp, ws, out);
    }
}

// Round 3
// 197.604 us; speedup vs baseline: 3.5466x; 1.0044x over previous
//
#include <hip/hip_runtime.h>
#include <hip/hip_bf16.h>

typedef __attribute__((ext_vector_type(4))) float f32x4;
typedef __attribute__((ext_vector_type(8))) short s16x8;

#define MFMA16(a, b, c) __builtin_amdgcn_mfma_f32_16x16x32_bf16(a, b, c, 0, 0, 0)

#define DG 256
#define NE 16
#define NN 17
#define TB 32
#define NTOK 8192

// ws float offsets (small data)
#define WS_S    0        // S [17][256]
#define WS_A    4352     // a [17]
#define WS_AD   4376     // A dense [17*17]
#define WS_EW   8768     // exp@W1 [16][256]
// ws byte offsets (pre-swizzled bf16 hi/lo weight fragments)
#define FB_WMH  65536
#define FB_WML  589824
#define FB_W1H  1114112
#define FB_W1L  1245184
#define FB_W2H  1376256
#define FB_W2L  1507328
#define WS_NEED 1638400

// ---------- slow-path scalar RNE helpers (setup + fallback only) ----------
__device__ __forceinline__ ushort bf16h(float f) {
    union { float f; uint u; } c; c.f = f;
    return (ushort)((c.u + 0x7fffu + ((c.u >> 16) & 1u)) >> 16);  // RNE
}
__device__ __forceinline__ float bf16tof(ushort h) {
    union { uint u; float f; } c; c.u = (uint)h << 16;
    return c.f;
}
__device__ __forceinline__ void cvt_hilo(f32x4 a, f32x4 b, s16x8& hi, s16x8& lo) {
#pragma unroll
    for (int i = 0; i < 4; ++i) {
        const ushort h = bf16h(a[i]);
        hi[i] = (short)h;
        lo[i] = (short)bf16h(a[i] - bf16tof(h));
    }
#pragma unroll
    for (int i = 0; i < 4; ++i) {
        const ushort h = bf16h(b[i]);
        hi[4 + i] = (short)h;
        lo[4 + i] = (short)bf16h(b[i] - bf16tof(h));
    }
}

// ---------- fast packed converters (v_cvt_pk_bf16_f32 via hip_bf16) ----------
__device__ __forceinline__ uint pkbf(float a, float b) {
    __hip_bfloat162 t = __float22bfloat162_rn(make_float2(a, b));
    return *reinterpret_cast<uint*>(&t);
}
__device__ __forceinline__ void cvt_hilo_pk(f32x4 v0, f32x4 v1, s16x8& hi, s16x8& lo) {
    uint* hu = reinterpret_cast<uint*>(&hi);
    uint* lu = reinterpret_cast<uint*>(&lo);
    float a[8];
    *(f32x4*)a = v0; *(f32x4*)(a + 4) = v1;
#pragma unroll
    for (int i = 0; i < 4; ++i) {
        const uint h = pkbf(a[2 * i], a[2 * i + 1]);
        hu[i] = h;
        union { uint u; float f; } fa, fb;
        fa.u = h << 16; fb.u = h & 0xffff0000u;
        lu[i] = pkbf(a[2 * i] - fa.f, a[2 * i + 1] - fb.f);
    }
}

// B-operand fragment: b[i] = W[ks*32 + 8*(lane>>4) + i][nt*16 + (lane&15)]
template<bool SWZ>
__device__ __forceinline__ void loadB(const ushort* __restrict__ H,
                                      const ushort* __restrict__ L,
                                      const float* __restrict__ Wf,
                                      int KST, int nt, int ks, int lane,
                                      s16x8& bh, s16x8& bl) {
    if (SWZ) {
        const size_t off = ((size_t)(nt * KST + ks) * 64 + lane) * 8;
        bh = *(const s16x8*)(H + off);
        bl = *(const s16x8*)(L + off);
    } else {
        const int k0 = ks * 32 + ((lane >> 4) << 3);
        const int col = nt * 16 + (lane & 15);
        const float* p = Wf + (size_t)k0 * DG + col;
        f32x4 v0, v1;
#pragma unroll
        for (int i = 0; i < 4; ++i) v0[i] = p[(size_t)i * DG];
#pragma unroll
        for (int i = 0; i < 4; ++i) v1[i] = p[(size_t)(4 + i) * DG];
        cvt_hilo(v0, v1, bh, bl);
    }
}

// ---------------- setup kernel 1: block e -> exp[e], ew[e] = exp[e] @ W1 ----------------
__global__ __launch_bounds__(512) void k_se1(const float* __restrict__ X,
                                             const float* __restrict__ Wst,
                                             const float* __restrict__ W1,
                                             float* __restrict__ ws) {
    const int e = blockIdx.x, tid = threadIdx.x;
    const int d = tid & 255, half = tid >> 8;
    __shared__ float xr[1024];
    __shared__ float part[2][256];
    __shared__ float er[256];

    *(float2*)&xr[tid * 2] = *(const float2*)&X[e * 1024 + tid * 2];
    __syncthreads();
    float acc = 0.f;
    const int k0 = half * 512;
    for (int k = 0; k < 512; ++k)
        acc = fmaf(xr[k0 + k], Wst[(size_t)(k0 + k) * DG + d], acc);
    part[half][d] = acc;
    __syncthreads();
    if (tid < 256) er[tid] = fmaxf(part[0][tid] + part[1][tid], 0.f);
    __syncthreads();
    float a2 = 0.f;
    const int m0 = half * 128;
    for (int m = 0; m < 128; ++m)
        a2 = fmaf(er[m0 + m], W1[(size_t)(m0 + m) * DG + d], a2);
    part[half][d] = a2;
    __syncthreads();
    if (tid < 256) ws[WS_EW + e * DG + tid] = part[0][tid] + part[1][tid];
}

// ---------------- setup kernel 2: blocks 0..17 adjacency/S; blocks 18+ swizzle ----------------
__global__ __launch_bounds__(256) void k_se2(const float* __restrict__ adj,
                                             const float* __restrict__ Wm,
                                             const float* __restrict__ W1,
                                             const float* __restrict__ W2,
                                             float* __restrict__ ws) {
    const int b = blockIdx.x, tid = threadIdx.x;
    if (b >= 18) {
        const int local = (b - 18) * 256 + tid;
        const float* W; ushort* H; ushort* L; int lo2, KST;
        char* base = (char*)ws;
        if (local < 262144)      { W = Wm; KST = 32; lo2 = local;          H = (ushort*)(base + FB_WMH); L = (ushort*)(base + FB_WML); }
        else if (local < 327680) { W = W1; KST = 8;  lo2 = local - 262144; H = (ushort*)(base + FB_W1H); L = (ushort*)(base + FB_W1L); }
        else                     { W = W2; KST = 8;  lo2 = local - 327680; H = (ushort*)(base + FB_W2H); L = (ushort*)(base + FB_W2L); }
        const int i = lo2 & 7, l = (lo2 >> 3) & 63, t = lo2 >> 9;
        const int ks = t % KST, nt = t / KST;
        const int k = ks * 32 + ((l >> 4) << 3) + i;
        const int col = nt * 16 + (l & 15);
        const float wv = W[(size_t)k * DG + col];
        const ushort h = bf16h(wv);
        H[lo2] = h;
        L[lo2] = bf16h(wv - bf16tof(h));
        return;
    }
    __shared__ float dinv[NN];
    __shared__ float row[NN];
    if (tid < NN) {
        float deg = 0.f;
        for (int m = 0; m < NN; ++m) deg += adj[tid * NN + m];
        dinv[tid] = 1.0f / sqrtf(deg);
    }
    __syncthreads();
    if (b < NN) {
        if (tid < NN) row[tid] = adj[b * NN + tid] * dinv[b] * dinv[tid];
        __syncthreads();
        float s = 0.f;
        for (int e = 0; e < NE; ++e) s = fmaf(row[e], ws[WS_EW + e * DG + tid], s);
        ws[WS_S + b * DG + tid] = s;
    } else {
        if (tid < NN) ws[WS_A + tid] = adj[tid * NN + NE] * dinv[tid] * dinv[NE];
        for (int i = tid; i < NN * NN; i += 256)
            ws[WS_AD + i] = adj[i] * dinv[i / NN] * dinv[i % NN];
    }
}

// ---------------- fused main kernel ----------------
template<bool SWZ>
__global__ __launch_bounds__(512, 2) void k_main(
        const float* __restrict__ x,
        const float* __restrict__ Wm,
        const float* __restrict__ W1,
        const float* __restrict__ W2,
        const float* __restrict__ Wp,
        const float* __restrict__ ws,
        float* __restrict__ out) {
    const int tid = threadIdx.x;
    const int lane = tid & 63, w = tid >> 6;
    const int r16 = lane & 15, g4 = lane >> 4;
    const int nt0 = 2 * w, nt1 = nt0 + 1;
    const size_t t0 = (size_t)blockIdx.x * TB;

    __shared__ float S_s[NN][260];                                    // 17680 B
    __shared__ float g_s[TB][260];                                    // 33280 B
    __shared__ alignas(16) union {
        float h[TB][260];                                             // 33280 B
        ushort frag[2][NN * 64 * 8];                                  // 34816 B (dbuf)
    } U;
    __shared__ float part[8][16][NE];                                 // 8192 B
    __shared__ float a_l[NN];
    __shared__ float Ad_l[NN * NN];

    for (int j = tid; j < NN * DG; j += 512) S_s[j >> 8][j & 255] = ws[WS_S + j];
    if (tid < NN) a_l[tid] = ws[WS_A + tid];
    for (int j = tid; j < NN * NN; j += 512) Ad_l[j] = ws[WS_AD + j];

    const char* base = (const char*)ws;
    const ushort* WmH = (const ushort*)(base + FB_WMH);
    const ushort* WmL = (const ushort*)(base + FB_WML);
    const ushort* W1H = (const ushort*)(base + FB_W1H);
    const ushort* W1L = (const ushort*)(base + FB_W1L);
    const ushort* W2H = (const ushort*)(base + FB_W2H);
    const ushort* W2L = (const ushort*)(base + FB_W2L);

    // ---- phase A: h = relu(x @ Wm), M=32 K=1024 ----
    f32x4 hacc[2][2];
#pragma unroll
    for (int mt = 0; mt < 2; ++mt)
#pragma unroll
        for (int j = 0; j < 2; ++j) hacc[mt][j] = (f32x4){0.f, 0.f, 0.f, 0.f};

    for (int ks = 0; ks < 32; ++ks) {
        s16x8 ah[2], aL[2];
#pragma unroll
        for (int mt = 0; mt < 2; ++mt) {
            const float* px = x + (t0 + mt * 16 + r16) * 1024 + ks * 32 + g4 * 8;
            cvt_hilo_pk(*(const f32x4*)px, *(const f32x4*)(px + 4), ah[mt], aL[mt]);
        }
        s16x8 bh[2], bl[2];
        loadB<SWZ>(WmH, WmL, Wm, 32, nt0, ks, lane, bh[0], bl[0]);
        loadB<SWZ>(WmH, WmL, Wm, 32, nt1, ks, lane, bh[1], bl[1]);
#pragma unroll
        for (int mt = 0; mt < 2; ++mt)
#pragma unroll
            for (int j = 0; j < 2; ++j) {
                hacc[mt][j] = MFMA16(ah[mt], bh[j], hacc[mt][j]);
                hacc[mt][j] = MFMA16(aL[mt], bh[j], hacc[mt][j]);
                hacc[mt][j] = MFMA16(ah[mt], bl[j], hacc[mt][j]);
            }
    }
#pragma unroll
    for (int mt = 0; mt < 2; ++mt)
#pragma unroll
        for (int j = 0; j < 2; ++j)
#pragma unroll
            for (int r = 0; r < 4; ++r)
                U.h[mt * 16 + g4 * 4 + r][(nt0 + j) * 16 + r16] = fmaxf(hacc[mt][j][r], 0.f);
    __syncthreads();

    // ---- phase B: g = h @ W1 (no relu), K=256 ----
    f32x4 gacc[2][2];
#pragma unroll
    for (int mt = 0; mt < 2; ++mt)
#pragma unroll
        for (int j = 0; j < 2; ++j) gacc[mt][j] = (f32x4){0.f, 0.f, 0.f, 0.f};

    for (int ks = 0; ks < 8; ++ks) {
        s16x8 ah[2], aL[2];
#pragma unroll
        for (int mt = 0; mt < 2; ++mt) {
            const float* ph = &U.h[mt * 16 + r16][ks * 32 + g4 * 8];
            cvt_hilo_pk(*(const f32x4*)ph, *(const f32x4*)(ph + 4), ah[mt], aL[mt]);
        }
        s16x8 bh[2], bl[2];
        loadB<SWZ>(W1H, W1L, W1, 8, nt0, ks, lane, bh[0], bl[0]);
        loadB<SWZ>(W1H, W1L, W1, 8, nt1, ks, lane, bh[1], bl[1]);
#pragma unroll
        for (int mt = 0; mt < 2; ++mt)
#pragma unroll
            for (int j = 0; j < 2; ++j) {
                gacc[mt][j] = MFMA16(ah[mt], bh[j], gacc[mt][j]);
                gacc[mt][j] = MFMA16(aL[mt], bh[j], gacc[mt][j]);
                gacc[mt][j] = MFMA16(ah[mt], bl[j], gacc[mt][j]);
            }
    }
#pragma unroll
    for (int mt = 0; mt < 2; ++mt)
#pragma unroll
        for (int j = 0; j < 2; ++j)
#pragma unroll
            for (int r = 0; r < 4; ++r)
                g_s[mt * 16 + g4 * 4 + r][(nt0 + j) * 16 + r16] = gacc[mt][j][r];
    __syncthreads();

    const float wp0 = Wp[nt0 * 16 + r16], wp1 = Wp[nt1 * 16 + r16];
    uint* const fragU0 = (uint*)U.frag[0];
    uint* const fragU1 = (uint*)U.frag[1];

    // ---- phases C/D/E per 16-token sub-batch; M-tile n = 16 tokens of node n ----
    for (int sb = 0; sb < 2; ++sb) {
        f32x4 acc[NN][2];
#pragma unroll
        for (int n = 0; n < NN; ++n) {
            acc[n][0] = (f32x4){0.f, 0.f, 0.f, 0.f};
            acc[n][1] = (f32x4){0.f, 0.f, 0.f, 0.f};
        }
        for (int ks = 0; ks < 8; ++ks) {
            // prefetch W2 B-frags (independent of the build)
            s16x8 bh0, bl0, bh1, bl1;
            loadB<SWZ>(W2H, W2L, W2, 8, nt0, ks, lane, bh0, bl0);
            loadB<SWZ>(W2H, W2L, W2, 8, nt1, ks, lane, bh1, bl1);

            // build single-bf16 y1 fragments into frag[ks&1]
            uint* fr = (ks & 1) ? fragU1 : fragU0;
            for (int p = tid; p < NN * 256; p += 512) {
                const int n = p >> 8, rem = p & 255;
                const int l = rem >> 2, ip = rem & 3;
                const int k = ks * 32 + ((l >> 4) << 3) + ip * 2;
                const int row = sb * 16 + (l & 15);
                const float an = a_l[n];
                const float y0 = fmaxf(fmaf(an, g_s[row][k],     S_s[n][k]),     0.f);
                const float y1v = fmaxf(fmaf(an, g_s[row][k + 1], S_s[n][k + 1]), 0.f);
                fr[p] = pkbf(y0, y1v);
            }
            __syncthreads();

            // consume
            const ushort* fb = (ks & 1) ? U.frag[1] : U.frag[0];
#pragma unroll
            for (int n = 0; n < NN; ++n) {
                const s16x8 ah = *(const s16x8*)&fb[(n * 64 + lane) * 8];
                acc[n][0] = MFMA16(ah, bh0, acc[n][0]);
                acc[n][1] = MFMA16(ah, bh1, acc[n][1]);
                acc[n][0] = MFMA16(ah, bl0, acc[n][0]);
                acc[n][1] = MFMA16(ah, bl1, acc[n][1]);
            }
        }
        // ---- phase E: y2 = relu(A @ z); score = y2 . Wp ----
        for (int e = 0; e < NE; ++e) {
            f32x4 z0 = (f32x4){0.f, 0.f, 0.f, 0.f}, z1 = (f32x4){0.f, 0.f, 0.f, 0.f};
#pragma unroll
            for (int n = 0; n < NN; ++n) {
                const float av = Ad_l[e * NN + n];
                if (av != 0.f) {   // uniform branch; A is sparse
#pragma unroll
                    for (int r = 0; r < 4; ++r) {
                        z0[r] = fmaf(av, acc[n][0][r], z0[r]);
                        z1[r] = fmaf(av, acc[n][1][r], z1[r]);
                    }
                }
            }
            float v[4];
#pragma unroll
            for (int r = 0; r < 4; ++r)
                v[r] = fmaxf(z0[r], 0.f) * wp0 + fmaxf(z1[r], 0.f) * wp1;
#pragma unroll
            for (int off = 1; off < 16; off <<= 1)
#pragma unroll
                for (int r = 0; r < 4; ++r) v[r] += __shfl_xor(v[r], off, 64);
            if (r16 == 0)
#pragma unroll
                for (int r = 0; r < 4; ++r) part[w][g4 * 4 + r][e] = v[r];
        }
        __syncthreads();
        if (tid < 256) {
            const int t = tid >> 4, e = tid & 15;
            float s = 0.f;
#pragma unroll
            for (int q = 0; q < 8; ++q) s += part[q][t][e];
            out[(t0 + sb * 16 + t) * NE + e] = s;
        }
        __syncthreads();   // part/frag reuse guard for next sb
    }
}

extern "C" void kernel_launch(void* const* d_in, const int* in_sizes, int n_in,
                              void* d_out, int out_size, void* d_ws, size_t ws_size,
                              hipStream_t stream) {
    const float* x   = (const float*)d_in[0];
    const float* X   = (const float*)d_in[1];
    const float* Wm  = (const float*)d_in[2];
    const float* Wst = (const float*)d_in[3];
    const float* Wc  = (const float*)d_in[4];
    const float* Wp  = (const float*)d_in[5];
    const float* adj = (const float*)d_in[6];
    float* out = (float*)d_out;
    float* ws  = (float*)d_ws;
    const float* W1 = Wc;
    const float* W2 = Wc + DG * DG;

    k_se1<<<NE, 512, 0, stream>>>(X, Wst, W1, ws);

    if (ws_size >= (size_t)WS_NEED) {
        k_se2<<<18 + 1536, 256, 0, stream>>>(adj, Wm, W1, W2, ws);
        k_main<true><<<NTOK / TB, 512, 0, stream>>>(x, Wm, W1, W2, Wp, ws, out);
    } else {
        k_se2<<<18, 256, 0, stream>>>(adj, Wm, W1, W2, ws);
        k_main<false><<<NTOK / TB, 512, 0, stream>>>(x, Wm, W1, W2, Wp, ws, out);
    }
}

// Round 4
// 145.525 us; speedup vs baseline: 4.8159x; 1.3579x over previous
//
#include <hip/hip_runtime.h>
#include <hip/hip_bf16.h>

typedef __attribute__((ext_vector_type(4))) float f32x4;
typedef __attribute__((ext_vector_type(8))) short s16x8;
typedef __attribute__((ext_vector_type(4))) uint u32x4;

#define MFMA16(a, b, c) __builtin_amdgcn_mfma_f32_16x16x32_bf16(a, b, c, 0, 0, 0)

#define DG 256
#define NE 16
#define NN 17
#define TB 32
#define NTOK 8192

// ws float offsets (small data)
#define WS_S    0        // S [17][256]
#define WS_A    4352     // a [17]
#define WS_AD   4376     // A dense [17*17]
#define WS_EW   8768     // exp@W1 [16][256]
// ws byte offsets (pre-swizzled bf16 hi/lo weight fragments)
#define FB_WMH  65536
#define FB_WML  589824
#define FB_W1H  1114112
#define FB_W1L  1245184
#define FB_W2H  1376256
#define FB_W2L  1507328
#define WS_NEED 1638400

// ---------- scalar RNE helpers (setup + fallback only) ----------
__device__ __forceinline__ ushort bf16h(float f) {
    union { float f; uint u; } c; c.f = f;
    return (ushort)((c.u + 0x7fffu + ((c.u >> 16) & 1u)) >> 16);  // RNE
}
__device__ __forceinline__ float bf16tof(ushort h) {
    union { uint u; float f; } c; c.u = (uint)h << 16;
    return c.f;
}
__device__ __forceinline__ void cvt_hilo(f32x4 a, f32x4 b, s16x8& hi, s16x8& lo) {
#pragma unroll
    for (int i = 0; i < 4; ++i) {
        const ushort h = bf16h(a[i]);
        hi[i] = (short)h;
        lo[i] = (short)bf16h(a[i] - bf16tof(h));
    }
#pragma unroll
    for (int i = 0; i < 4; ++i) {
        const ushort h = bf16h(b[i]);
        hi[4 + i] = (short)h;
        lo[4 + i] = (short)bf16h(b[i] - bf16tof(h));
    }
}

// ---------- fast packed converters (v_cvt_pk_bf16_f32) ----------
__device__ __forceinline__ uint pkbf(float a, float b) {
    __hip_bfloat162 t = __float22bfloat162_rn(make_float2(a, b));
    return *reinterpret_cast<uint*>(&t);
}
__device__ __forceinline__ void cvt_hilo_pk(f32x4 v0, f32x4 v1, s16x8& hi, s16x8& lo) {
    uint* hu = reinterpret_cast<uint*>(&hi);
    uint* lu = reinterpret_cast<uint*>(&lo);
    float a[8];
    *(f32x4*)a = v0; *(f32x4*)(a + 4) = v1;
#pragma unroll
    for (int i = 0; i < 4; ++i) {
        const uint h = pkbf(a[2 * i], a[2 * i + 1]);
        hu[i] = h;
        union { uint u; float f; } fa, fb;
        fa.u = h << 16; fb.u = h & 0xffff0000u;
        lu[i] = pkbf(a[2 * i] - fa.f, a[2 * i + 1] - fb.f);
    }
}

// B-operand fragment: b[i] = W[ks*32 + 8*(lane>>4) + i][nt*16 + (lane&15)]
template<bool SWZ>
__device__ __forceinline__ void loadB(const ushort* __restrict__ H,
                                      const ushort* __restrict__ L,
                                      const float* __restrict__ Wf,
                                      int KST, int nt, int ks, int lane,
                                      s16x8& bh, s16x8& bl) {
    if (SWZ) {
        const size_t off = ((size_t)(nt * KST + ks) * 64 + lane) * 8;
        bh = *(const s16x8*)(H + off);
        bl = *(const s16x8*)(L + off);
    } else {
        const int k0 = ks * 32 + ((lane >> 4) << 3);
        const int col = nt * 16 + (lane & 15);
        const float* p = Wf + (size_t)k0 * DG + col;
        f32x4 v0, v1;
#pragma unroll
        for (int i = 0; i < 4; ++i) v0[i] = p[(size_t)i * DG];
#pragma unroll
        for (int i = 0; i < 4; ++i) v1[i] = p[(size_t)(4 + i) * DG];
        cvt_hilo(v0, v1, bh, bl);
    }
}

// ---------------- setup kernel 1: block e -> exp[e], ew[e] = exp[e] @ W1 ----------------
__global__ __launch_bounds__(512) void k_se1(const float* __restrict__ X,
                                             const float* __restrict__ Wst,
                                             const float* __restrict__ W1,
                                             float* __restrict__ ws) {
    const int e = blockIdx.x, tid = threadIdx.x;
    const int d = tid & 255, half = tid >> 8;
    __shared__ float xr[1024];
    __shared__ float part[2][256];
    __shared__ float er[256];

    *(float2*)&xr[tid * 2] = *(const float2*)&X[e * 1024 + tid * 2];
    __syncthreads();
    float acc = 0.f;
    const int k0 = half * 512;
    for (int k = 0; k < 512; ++k)
        acc = fmaf(xr[k0 + k], Wst[(size_t)(k0 + k) * DG + d], acc);
    part[half][d] = acc;
    __syncthreads();
    if (tid < 256) er[tid] = fmaxf(part[0][tid] + part[1][tid], 0.f);
    __syncthreads();
    float a2 = 0.f;
    const int m0 = half * 128;
    for (int m = 0; m < 128; ++m)
        a2 = fmaf(er[m0 + m], W1[(size_t)(m0 + m) * DG + d], a2);
    part[half][d] = a2;
    __syncthreads();
    if (tid < 256) ws[WS_EW + e * DG + tid] = part[0][tid] + part[1][tid];
}

// ---------------- setup kernel 2: blocks 0..17 adjacency/S; blocks 18+ swizzle ----------------
__global__ __launch_bounds__(256) void k_se2(const float* __restrict__ adj,
                                             const float* __restrict__ Wm,
                                             const float* __restrict__ W1,
                                             const float* __restrict__ W2,
                                             float* __restrict__ ws) {
    const int b = blockIdx.x, tid = threadIdx.x;
    if (b >= 18) {
        const int local = (b - 18) * 256 + tid;
        const float* W; ushort* H; ushort* L; int lo2, KST;
        char* base = (char*)ws;
        if (local < 262144)      { W = Wm; KST = 32; lo2 = local;          H = (ushort*)(base + FB_WMH); L = (ushort*)(base + FB_WML); }
        else if (local < 327680) { W = W1; KST = 8;  lo2 = local - 262144; H = (ushort*)(base + FB_W1H); L = (ushort*)(base + FB_W1L); }
        else                     { W = W2; KST = 8;  lo2 = local - 327680; H = (ushort*)(base + FB_W2H); L = (ushort*)(base + FB_W2L); }
        const int i = lo2 & 7, l = (lo2 >> 3) & 63, t = lo2 >> 9;
        const int ks = t % KST, nt = t / KST;
        const int k = ks * 32 + ((l >> 4) << 3) + i;
        const int col = nt * 16 + (l & 15);
        const float wv = W[(size_t)k * DG + col];
        const ushort h = bf16h(wv);
        H[lo2] = h;
        L[lo2] = bf16h(wv - bf16tof(h));
        return;
    }
    __shared__ float dinv[NN];
    __shared__ float row[NN];
    if (tid < NN) {
        float deg = 0.f;
        for (int m = 0; m < NN; ++m) deg += adj[tid * NN + m];
        dinv[tid] = 1.0f / sqrtf(deg);
    }
    __syncthreads();
    if (b < NN) {
        if (tid < NN) row[tid] = adj[b * NN + tid] * dinv[b] * dinv[tid];
        __syncthreads();
        float s = 0.f;
        for (int e = 0; e < NE; ++e) s = fmaf(row[e], ws[WS_EW + e * DG + tid], s);
        ws[WS_S + b * DG + tid] = s;
    } else {
        if (tid < NN) ws[WS_A + tid] = adj[tid * NN + NE] * dinv[tid] * dinv[NE];
        for (int i = tid; i < NN * NN; i += 256)
            ws[WS_AD + i] = adj[i] * dinv[i / NN] * dinv[i % NN];
    }
}

// ---------------- fused main kernel: 1024 thr, 16 waves, TB=32, grid=256 ----------------
template<bool SWZ>
__global__ __launch_bounds__(1024, 4) void k_main(
        const float* __restrict__ x,
        const float* __restrict__ Wm,
        const float* __restrict__ W1,
        const float* __restrict__ W2,
        const float* __restrict__ Wp,
        const float* __restrict__ ws,
        float* __restrict__ out) {
    const int tid = threadIdx.x;
    const int lane = tid & 63, w = tid >> 6;          // wave = N-tile 0..15
    const int r16 = lane & 15, g4 = lane >> 4;
    const size_t t0 = (size_t)blockIdx.x * TB;

    __shared__ float S_s[NN][260];                    // 17680 B
    __shared__ float g_s[TB][260];                    // 33280 B
    __shared__ alignas(16) union {
        struct { ushort H[8][2][64][8]; ushort L[8][2][64][8]; } xf;  // 32768 B (x / h frags)
        ushort frag[2][NN * 64 * 8];                  // 34816 B (y1 dbuf)
    } U;
    __shared__ float part[16][16][NE];                // 16384 B
    __shared__ float a_l[NN];
    __shared__ float Ad_l[NN * NN];

    // staging constants: thread -> (row, 8-wide k segment) of the x chunk
    const int xrow = tid >> 5;                        // 0..31
    const int xk0 = (tid & 31) * 8;                   // 0..248
    const int sks = xk0 >> 5;
    const int sl = (((xk0 >> 3) & 3) << 4) | (xrow & 15);
    const int smt = xrow >> 4;

    for (int j = tid; j < NN * DG; j += 1024) S_s[j >> 8][j & 255] = ws[WS_S + j];
    if (tid < NN) a_l[tid] = ws[WS_A + tid];
    for (int j = tid; j < NN * NN; j += 1024) Ad_l[j] = ws[WS_AD + j];

    const char* base = (const char*)ws;
    const ushort* WmH = (const ushort*)(base + FB_WMH);
    const ushort* WmL = (const ushort*)(base + FB_WML);
    const ushort* W1H = (const ushort*)(base + FB_W1H);
    const ushort* W1L = (const ushort*)(base + FB_W1L);
    const ushort* W2H = (const ushort*)(base + FB_W2H);
    const ushort* W2L = (const ushort*)(base + FB_W2L);

    // stage x chunk 0 (cooperative convert-once)
    {
        const float* px = x + (t0 + xrow) * 1024 + xk0;
        s16x8 hi, lo;
        cvt_hilo_pk(*(const f32x4*)px, *(const f32x4*)(px + 4), hi, lo);
        *(s16x8*)&U.xf.H[sks][smt][sl][0] = hi;
        *(s16x8*)&U.xf.L[sks][smt][sl][0] = lo;
    }
    __syncthreads();

    // ---- phase A: h = relu(x @ Wm), M=32 K=1024, 4 chunks of 256 ----
    f32x4 hacc[2];
    hacc[0] = (f32x4){0.f, 0.f, 0.f, 0.f};
    hacc[1] = (f32x4){0.f, 0.f, 0.f, 0.f};
    for (int c = 0; c < 4; ++c) {
        f32x4 xn0, xn1;
        if (c < 3) {   // issue next chunk's loads early; cvt+write after consume
            const float* px = x + (t0 + xrow) * 1024 + (c + 1) * 256 + xk0;
            xn0 = *(const f32x4*)px;
            xn1 = *(const f32x4*)(px + 4);
        }
        for (int k8 = 0; k8 < 8; ++k8) {
            s16x8 bh, bl;
            loadB<SWZ>(WmH, WmL, Wm, 32, w, c * 8 + k8, lane, bh, bl);
#pragma unroll
            for (int mt = 0; mt < 2; ++mt) {
                const s16x8 ah = *(const s16x8*)&U.xf.H[k8][mt][lane][0];
                const s16x8 aL = *(const s16x8*)&U.xf.L[k8][mt][lane][0];
                hacc[mt] = MFMA16(ah, bh, hacc[mt]);
                hacc[mt] = MFMA16(aL, bh, hacc[mt]);
                hacc[mt] = MFMA16(ah, bl, hacc[mt]);
            }
        }
        __syncthreads();
        if (c < 3) {
            s16x8 hi, lo;
            cvt_hilo_pk(xn0, xn1, hi, lo);
            *(s16x8*)&U.xf.H[sks][smt][sl][0] = hi;
            *(s16x8*)&U.xf.L[sks][smt][sl][0] = lo;
            __syncthreads();
        }
    }

    // write h (relu) directly as hi/lo MFMA A-fragments into xf (xf is dead now)
    {
        const int ksB = w >> 1;
        const int cb = (w * 2 + (r16 >> 3)) & 3;
        const int ie = r16 & 7;
#pragma unroll
        for (int mt = 0; mt < 2; ++mt) {
            const float hv0 = fmaxf(hacc[mt][0], 0.f), hv1 = fmaxf(hacc[mt][1], 0.f);
            const float hv2 = fmaxf(hacc[mt][2], 0.f), hv3 = fmaxf(hacc[mt][3], 0.f);
            const uint p01 = pkbf(hv0, hv1), p23 = pkbf(hv2, hv3);
            union { uint u; float f; } b0, b1, b2, b3;
            b0.u = p01 << 16; b1.u = p01 & 0xffff0000u;
            b2.u = p23 << 16; b3.u = p23 & 0xffff0000u;
            const uint q01 = pkbf(hv0 - b0.f, hv1 - b1.f);
            const uint q23 = pkbf(hv2 - b2.f, hv3 - b3.f);
            const int lr = cb * 16 + g4 * 4;
            U.xf.H[ksB][mt][lr + 0][ie] = (ushort)p01;
            U.xf.H[ksB][mt][lr + 1][ie] = (ushort)(p01 >> 16);
            U.xf.H[ksB][mt][lr + 2][ie] = (ushort)p23;
            U.xf.H[ksB][mt][lr + 3][ie] = (ushort)(p23 >> 16);
            U.xf.L[ksB][mt][lr + 0][ie] = (ushort)q01;
            U.xf.L[ksB][mt][lr + 1][ie] = (ushort)(q01 >> 16);
            U.xf.L[ksB][mt][lr + 2][ie] = (ushort)q23;
            U.xf.L[ksB][mt][lr + 3][ie] = (ushort)(q23 >> 16);
        }
    }
    __syncthreads();

    // ---- phase B: g = h @ W1 (no relu), K=256 ----
    f32x4 gacc[2];
    gacc[0] = (f32x4){0.f, 0.f, 0.f, 0.f};
    gacc[1] = (f32x4){0.f, 0.f, 0.f, 0.f};
    for (int k8 = 0; k8 < 8; ++k8) {
        s16x8 bh, bl;
        loadB<SWZ>(W1H, W1L, W1, 8, w, k8, lane, bh, bl);
#pragma unroll
        for (int mt = 0; mt < 2; ++mt) {
            const s16x8 ah = *(const s16x8*)&U.xf.H[k8][mt][lane][0];
            const s16x8 aL = *(const s16x8*)&U.xf.L[k8][mt][lane][0];
            gacc[mt] = MFMA16(ah, bh, gacc[mt]);
            gacc[mt] = MFMA16(aL, bh, gacc[mt]);
            gacc[mt] = MFMA16(ah, bl, gacc[mt]);
        }
    }
#pragma unroll
    for (int mt = 0; mt < 2; ++mt)
#pragma unroll
        for (int r = 0; r < 4; ++r)
            g_s[mt * 16 + g4 * 4 + r][w * 16 + r16] = gacc[mt][r];
    __syncthreads();   // g_s ready + xf reads done (frag overlays xf next)

    const float wp = Wp[w * 16 + r16];

    // ---- phases C/D/E per 16-token sub-batch; M-tile n = 16 tokens of node n ----
    for (int sb = 0; sb < 2; ++sb) {
        f32x4 acc[NN];
#pragma unroll
        for (int n = 0; n < NN; ++n) acc[n] = (f32x4){0.f, 0.f, 0.f, 0.f};

        for (int ks = 0; ks < 8; ++ks) {
            s16x8 bh, bl;
            loadB<SWZ>(W2H, W2L, W2, 8, w, ks, lane, bh, bl);

            // build single-bf16 y1 fragments (vectorized, one b128 per slot)
            ushort* fr = U.frag[(sb * 8 + ks) & 1];
            for (int s = tid; s < NN * 64; s += 1024) {
                const int n = s >> 6, l = s & 63;
                const int row = sb * 16 + (l & 15);
                const int k0 = ks * 32 + ((l >> 4) << 3);
                const f32x4 G0 = *(const f32x4*)&g_s[row][k0];
                const f32x4 G1 = *(const f32x4*)&g_s[row][k0 + 4];
                const f32x4 Sa = *(const f32x4*)&S_s[n][k0];
                const f32x4 Sb = *(const f32x4*)&S_s[n][k0 + 4];
                const float an = a_l[n];
                u32x4 uu;
                uu[0] = pkbf(fmaxf(fmaf(an, G0[0], Sa[0]), 0.f),
                             fmaxf(fmaf(an, G0[1], Sa[1]), 0.f));
                uu[1] = pkbf(fmaxf(fmaf(an, G0[2], Sa[2]), 0.f),
                             fmaxf(fmaf(an, G0[3], Sa[3]), 0.f));
                uu[2] = pkbf(fmaxf(fmaf(an, G1[0], Sb[0]), 0.f),
                             fmaxf(fmaf(an, G1[1], Sb[1]), 0.f));
                uu[3] = pkbf(fmaxf(fmaf(an, G1[2], Sb[2]), 0.f),
                             fmaxf(fmaf(an, G1[3], Sb[3]), 0.f));
                *(u32x4*)&fr[(size_t)s * 8] = uu;
            }
            __syncthreads();

            const ushort* fb = U.frag[(sb * 8 + ks) & 1];
#pragma unroll
            for (int n = 0; n < NN; ++n) {
                const s16x8 ah = *(const s16x8*)&fb[(n * 64 + lane) * 8];
                acc[n] = MFMA16(ah, bh, acc[n]);
                acc[n] = MFMA16(ah, bl, acc[n]);
            }
        }

        // ---- phase E: y2 = relu(A @ z); score = y2 . Wp ----
        for (int e = 0; e < NE; ++e) {
            f32x4 z = (f32x4){0.f, 0.f, 0.f, 0.f};
#pragma unroll
            for (int n = 0; n < NN; ++n) {
                const float av = Ad_l[e * NN + n];
                if (av != 0.f) {   // uniform branch; A is sparse
#pragma unroll
                    for (int r = 0; r < 4; ++r) z[r] = fmaf(av, acc[n][r], z[r]);
                }
            }
            float v[4];
#pragma unroll
            for (int r = 0; r < 4; ++r) v[r] = fmaxf(z[r], 0.f) * wp;
#pragma unroll
            for (int off = 1; off < 16; off <<= 1)
#pragma unroll
                for (int r = 0; r < 4; ++r) v[r] += __shfl_xor(v[r], off, 64);
            if (r16 == 0)
#pragma unroll
                for (int r = 0; r < 4; ++r) part[w][g4 * 4 + r][e] = v[r];
        }
        __syncthreads();
        if (tid < 256) {
            const int t = tid >> 4, e = tid & 15;
            float s2 = 0.f;
#pragma unroll
            for (int q = 0; q < 16; ++q) s2 += part[q][t][e];
            out[(t0 + sb * 16 + t) * NE + e] = s2;
        }
        // no trailing barrier needed: next write to `part` is 8 barriers away
    }
}

extern "C" void kernel_launch(void* const* d_in, const int* in_sizes, int n_in,
                              void* d_out, int out_size, void* d_ws, size_t ws_size,
                              hipStream_t stream) {
    const float* x   = (const float*)d_in[0];
    const float* X   = (const float*)d_in[1];
    const float* Wm  = (const float*)d_in[2];
    const float* Wst = (const float*)d_in[3];
    const float* Wc  = (const float*)d_in[4];
    const float* Wp  = (const float*)d_in[5];
    const float* adj = (const float*)d_in[6];
    float* out = (float*)d_out;
    float* ws  = (float*)d_ws;
    const float* W1 = Wc;
    const float* W2 = Wc + DG * DG;

    k_se1<<<NE, 512, 0, stream>>>(X, Wst, W1, ws);

    if (ws_size >= (size_t)WS_NEED) {
        k_se2<<<18 + 1536, 256, 0, stream>>>(adj, Wm, W1, W2, ws);
        k_main<true><<<NTOK / TB, 1024, 0, stream>>>(x, Wm, W1, W2, Wp, ws, out);
    } else {
        k_se2<<<18, 256, 0, stream>>>(adj, Wm, W1, W2, ws);
        k_main<false><<<NTOK / TB, 1024, 0, stream>>>(x, Wm, W1, W2, Wp, ws, out);
    }
}

// Round 5
// 138.158 us; speedup vs baseline: 5.0726x; 1.0533x over previous
//
#include <hip/hip_runtime.h>
#include <hip/hip_bf16.h>

typedef __attribute__((ext_vector_type(4))) float f32x4;
typedef __attribute__((ext_vector_type(8))) short s16x8;
typedef __attribute__((ext_vector_type(4))) uint u32x4;

#define MFMA16(a, b, c) __builtin_amdgcn_mfma_f32_16x16x32_bf16(a, b, c, 0, 0, 0)

#define DG 256
#define NE 16
#define NN 17
#define TB 32
#define NTOK 8192
#define PAD 276   // stride in floats; 276/4 mod 32 = 5 (odd) -> conflict-free row reads

// ws float offsets (small data)
#define WS_S    0        // S [17][256]
#define WS_A    4352     // a [17]
#define WS_AD   4376     // A dense [17*17]
#define WS_EW   8768     // exp@W1 [16][256]
// ws byte offsets (pre-swizzled bf16 hi/lo weight fragments)
#define FB_WMH  65536
#define FB_WML  589824
#define FB_W1H  1114112
#define FB_W1L  1245184
#define FB_W2H  1376256
#define FB_W2L  1507328
#define WS_NEED 1638400

// ---------- scalar RNE helpers (setup + fallback only) ----------
__device__ __forceinline__ ushort bf16h(float f) {
    union { float f; uint u; } c; c.f = f;
    return (ushort)((c.u + 0x7fffu + ((c.u >> 16) & 1u)) >> 16);  // RNE
}
__device__ __forceinline__ float bf16tof(ushort h) {
    union { uint u; float f; } c; c.u = (uint)h << 16;
    return c.f;
}
__device__ __forceinline__ void cvt_hilo(f32x4 a, f32x4 b, s16x8& hi, s16x8& lo) {
#pragma unroll
    for (int i = 0; i < 4; ++i) {
        const ushort h = bf16h(a[i]);
        hi[i] = (short)h;
        lo[i] = (short)bf16h(a[i] - bf16tof(h));
    }
#pragma unroll
    for (int i = 0; i < 4; ++i) {
        const ushort h = bf16h(b[i]);
        hi[4 + i] = (short)h;
        lo[4 + i] = (short)bf16h(b[i] - bf16tof(h));
    }
}

// ---------- fast packed converters (v_cvt_pk_bf16_f32) ----------
__device__ __forceinline__ uint pkbf(float a, float b) {
    __hip_bfloat162 t = __float22bfloat162_rn(make_float2(a, b));
    return *reinterpret_cast<uint*>(&t);
}
__device__ __forceinline__ void cvt_hilo_pk(f32x4 v0, f32x4 v1, s16x8& hi, s16x8& lo) {
    uint* hu = reinterpret_cast<uint*>(&hi);
    uint* lu = reinterpret_cast<uint*>(&lo);
    float a[8];
    *(f32x4*)a = v0; *(f32x4*)(a + 4) = v1;
#pragma unroll
    for (int i = 0; i < 4; ++i) {
        const uint h = pkbf(a[2 * i], a[2 * i + 1]);
        hu[i] = h;
        union { uint u; float f; } fa, fb;
        fa.u = h << 16; fb.u = h & 0xffff0000u;
        lu[i] = pkbf(a[2 * i] - fa.f, a[2 * i + 1] - fb.f);
    }
}

// B-operand fragment: b[i] = W[ks*32 + 8*(lane>>4) + i][nt*16 + (lane&15)]
template<bool SWZ>
__device__ __forceinline__ void loadB(const ushort* __restrict__ H,
                                      const ushort* __restrict__ L,
                                      const float* __restrict__ Wf,
                                      int KST, int nt, int ks, int lane,
                                      s16x8& bh, s16x8& bl) {
    if (SWZ) {
        const size_t off = ((size_t)(nt * KST + ks) * 64 + lane) * 8;
        bh = *(const s16x8*)(H + off);
        bl = *(const s16x8*)(L + off);
    } else {
        const int k0 = ks * 32 + ((lane >> 4) << 3);
        const int col = nt * 16 + (lane & 15);
        const float* p = Wf + (size_t)k0 * DG + col;
        f32x4 v0, v1;
#pragma unroll
        for (int i = 0; i < 4; ++i) v0[i] = p[(size_t)i * DG];
#pragma unroll
        for (int i = 0; i < 4; ++i) v1[i] = p[(size_t)(4 + i) * DG];
        cvt_hilo(v0, v1, bh, bl);
    }
}

template<bool SWZ>
__device__ __forceinline__ void loadBH(const ushort* __restrict__ H,
                                       const float* __restrict__ Wf,
                                       int KST, int nt, int ks, int lane,
                                       s16x8& bh) {
    if (SWZ) {
        bh = *(const s16x8*)(H + ((size_t)(nt * KST + ks) * 64 + lane) * 8);
    } else {
        const int k0 = ks * 32 + ((lane >> 4) << 3);
        const int col = nt * 16 + (lane & 15);
        const float* p = Wf + (size_t)k0 * DG + col;
#pragma unroll
        for (int i = 0; i < 8; ++i) bh[i] = (short)bf16h(p[(size_t)i * DG]);
    }
}

// ---------------- setup kernel 1: block e -> exp[e], ew[e] = exp[e] @ W1 ----------------
__global__ __launch_bounds__(512) void k_se1(const float* __restrict__ X,
                                             const float* __restrict__ Wst,
                                             const float* __restrict__ W1,
                                             float* __restrict__ ws) {
    const int e = blockIdx.x, tid = threadIdx.x;
    const int d = tid & 255, half = tid >> 8;
    __shared__ float xr[1024];
    __shared__ float part[2][256];
    __shared__ float er[256];

    *(float2*)&xr[tid * 2] = *(const float2*)&X[e * 1024 + tid * 2];
    __syncthreads();
    float acc = 0.f;
    const int k0 = half * 512;
    for (int k = 0; k < 512; ++k)
        acc = fmaf(xr[k0 + k], Wst[(size_t)(k0 + k) * DG + d], acc);
    part[half][d] = acc;
    __syncthreads();
    if (tid < 256) er[tid] = fmaxf(part[0][tid] + part[1][tid], 0.f);
    __syncthreads();
    float a2 = 0.f;
    const int m0 = half * 128;
    for (int m = 0; m < 128; ++m)
        a2 = fmaf(er[m0 + m], W1[(size_t)(m0 + m) * DG + d], a2);
    part[half][d] = a2;
    __syncthreads();
    if (tid < 256) ws[WS_EW + e * DG + tid] = part[0][tid] + part[1][tid];
}

// ---------------- setup kernel 2: blocks 0..17 adjacency/S; blocks 18+ swizzle ----------------
__global__ __launch_bounds__(256) void k_se2(const float* __restrict__ adj,
                                             const float* __restrict__ Wm,
                                             const float* __restrict__ W1,
                                             const float* __restrict__ W2,
                                             float* __restrict__ ws) {
    const int b = blockIdx.x, tid = threadIdx.x;
    if (b >= 18) {
        const int local = (b - 18) * 256 + tid;
        const float* W; ushort* H; ushort* L; int lo2, KST;
        char* base = (char*)ws;
        if (local < 262144)      { W = Wm; KST = 32; lo2 = local;          H = (ushort*)(base + FB_WMH); L = (ushort*)(base + FB_WML); }
        else if (local < 327680) { W = W1; KST = 8;  lo2 = local - 262144; H = (ushort*)(base + FB_W1H); L = (ushort*)(base + FB_W1L); }
        else                     { W = W2; KST = 8;  lo2 = local - 327680; H = (ushort*)(base + FB_W2H); L = (ushort*)(base + FB_W2L); }
        const int i = lo2 & 7, l = (lo2 >> 3) & 63, t = lo2 >> 9;
        const int ks = t % KST, nt = t / KST;
        const int k = ks * 32 + ((l >> 4) << 3) + i;
        const int col = nt * 16 + (l & 15);
        const float wv = W[(size_t)k * DG + col];
        const ushort h = bf16h(wv);
        H[lo2] = h;
        L[lo2] = bf16h(wv - bf16tof(h));
        return;
    }
    __shared__ float dinv[NN];
    __shared__ float row[NN];
    if (tid < NN) {
        float deg = 0.f;
        for (int m = 0; m < NN; ++m) deg += adj[tid * NN + m];
        dinv[tid] = 1.0f / sqrtf(deg);
    }
    __syncthreads();
    if (b < NN) {
        if (tid < NN) row[tid] = adj[b * NN + tid] * dinv[b] * dinv[tid];
        __syncthreads();
        float s = 0.f;
        for (int e = 0; e < NE; ++e) s = fmaf(row[e], ws[WS_EW + e * DG + tid], s);
        ws[WS_S + b * DG + tid] = s;
    } else {
        if (tid < NN) ws[WS_A + tid] = adj[tid * NN + NE] * dinv[tid] * dinv[NE];
        for (int i = tid; i < NN * NN; i += 256)
            ws[WS_AD + i] = adj[i] * dinv[i / NN] * dinv[i % NN];
    }
}

// ---------------- fused main kernel: 512 thr, 8 waves, TB=32, grid=256 ----------------
template<bool SWZ>
__global__ __launch_bounds__(512, 2) void k_main(
        const float* __restrict__ x,
        const float* __restrict__ Wm,
        const float* __restrict__ W1,
        const float* __restrict__ W2,
        const float* __restrict__ Wp,
        const float* __restrict__ ws,
        float* __restrict__ out) {
    const int tid = threadIdx.x;
    const int lane = tid & 63, w = tid >> 6;          // wave owns col-tiles 2w, 2w+1
    const int r16 = lane & 15, g4 = lane >> 4;
    const int nt0 = 2 * w, nt1 = 2 * w + 1;
    const size_t t0 = (size_t)blockIdx.x * TB;

    __shared__ float S_s[NN][PAD];                    // 18768 B
    __shared__ float g_s[TB][PAD];                    // 35328 B
    __shared__ alignas(16) union {
        struct { ushort H[8][2][64][8]; ushort L[8][2][64][8]; } xf;  // 32768 B
        ushort frag[NN * 64 * 8];                     // 17408 B (y1, single buf)
    } U;
    __shared__ float part[8][16][NE];                 // 8192 B
    __shared__ float a_l[NN];
    __shared__ float Ad_l[NN * NN];

    for (int j = tid; j < NN * DG; j += 512) S_s[j >> 8][j & 255] = ws[WS_S + j];
    if (tid < NN) a_l[tid] = ws[WS_A + tid];
    for (int j = tid; j < NN * NN; j += 512) Ad_l[j] = ws[WS_AD + j];

    const char* base = (const char*)ws;
    const ushort* WmH = (const ushort*)(base + FB_WMH);
    const ushort* WmL = (const ushort*)(base + FB_WML);
    const ushort* W1H = (const ushort*)(base + FB_W1H);
    const ushort* W1L = (const ushort*)(base + FB_W1L);
    const ushort* W2H = (const ushort*)(base + FB_W2H);

    // staging map: thread -> (row, 16-float segment); two lane-groups per thread
    const int srow = tid >> 4;                        // 0..31
    const int sq = tid & 15;                          // segment, k0 = 16*sq
    const int sk8 = sq >> 1;
    const int smt = srow >> 4;
    const int sr15 = srow & 15;
    const int slA = (((sq * 2) & 3) << 4) | sr15;
    const int slB = (((sq * 2 + 1) & 3) << 4) | sr15;

    // stage x chunk 0 (hi/lo, convert-once)
    {
        const float* px = x + (t0 + srow) * 1024 + sq * 16;
        s16x8 h0, l0, h1, l1;
        cvt_hilo_pk(*(const f32x4*)px, *(const f32x4*)(px + 4), h0, l0);
        cvt_hilo_pk(*(const f32x4*)(px + 8), *(const f32x4*)(px + 12), h1, l1);
        *(s16x8*)&U.xf.H[sk8][smt][slA][0] = h0;
        *(s16x8*)&U.xf.L[sk8][smt][slA][0] = l0;
        *(s16x8*)&U.xf.H[sk8][smt][slB][0] = h1;
        *(s16x8*)&U.xf.L[sk8][smt][slB][0] = l1;
    }
    __syncthreads();

    // ---- phase A: h = relu(x @ Wm), M=32 K=1024, 4 chunks of 256 ----
    f32x4 hacc[2][2];
#pragma unroll
    for (int mt = 0; mt < 2; ++mt)
#pragma unroll
        for (int j = 0; j < 2; ++j) hacc[mt][j] = (f32x4){0.f, 0.f, 0.f, 0.f};

    for (int c = 0; c < 4; ++c) {
        f32x4 xn0, xn1, xn2, xn3;
        if (c < 3) {   // issue next chunk's loads early; cvt+write after consume
            const float* px = x + (t0 + srow) * 1024 + (c + 1) * 256 + sq * 16;
            xn0 = *(const f32x4*)px;        xn1 = *(const f32x4*)(px + 4);
            xn2 = *(const f32x4*)(px + 8);  xn3 = *(const f32x4*)(px + 12);
        }
        for (int k8 = 0; k8 < 8; ++k8) {
            s16x8 bh0, bl0, bh1, bl1;
            loadB<SWZ>(WmH, WmL, Wm, 32, nt0, c * 8 + k8, lane, bh0, bl0);
            loadB<SWZ>(WmH, WmL, Wm, 32, nt1, c * 8 + k8, lane, bh1, bl1);
#pragma unroll
            for (int mt = 0; mt < 2; ++mt) {
                const s16x8 ah = *(const s16x8*)&U.xf.H[k8][mt][lane][0];
                const s16x8 aL = *(const s16x8*)&U.xf.L[k8][mt][lane][0];
                hacc[mt][0] = MFMA16(ah, bh0, hacc[mt][0]);
                hacc[mt][0] = MFMA16(aL, bh0, hacc[mt][0]);
                hacc[mt][0] = MFMA16(ah, bl0, hacc[mt][0]);
                hacc[mt][1] = MFMA16(ah, bh1, hacc[mt][1]);
                hacc[mt][1] = MFMA16(aL, bh1, hacc[mt][1]);
                hacc[mt][1] = MFMA16(ah, bl1, hacc[mt][1]);
            }
        }
        __syncthreads();
        if (c < 3) {
            s16x8 h0, l0, h1, l1;
            cvt_hilo_pk(xn0, xn1, h0, l0);
            cvt_hilo_pk(xn2, xn3, h1, l1);
            *(s16x8*)&U.xf.H[sk8][smt][slA][0] = h0;
            *(s16x8*)&U.xf.L[sk8][smt][slA][0] = l0;
            *(s16x8*)&U.xf.H[sk8][smt][slB][0] = h1;
            *(s16x8*)&U.xf.L[sk8][smt][slB][0] = l1;
            __syncthreads();
        }
    }

    // write h (relu) directly as hi/lo MFMA A-fragments; col (2w+j)*16+r16 -> k8B = w
    {
#pragma unroll
        for (int mt = 0; mt < 2; ++mt)
#pragma unroll
            for (int j = 0; j < 2; ++j) {
                const float hv0 = fmaxf(hacc[mt][j][0], 0.f), hv1 = fmaxf(hacc[mt][j][1], 0.f);
                const float hv2 = fmaxf(hacc[mt][j][2], 0.f), hv3 = fmaxf(hacc[mt][j][3], 0.f);
                const uint p01 = pkbf(hv0, hv1), p23 = pkbf(hv2, hv3);
                union { uint u; float f; } b0, b1, b2, b3;
                b0.u = p01 << 16; b1.u = p01 & 0xffff0000u;
                b2.u = p23 << 16; b3.u = p23 & 0xffff0000u;
                const uint q01 = pkbf(hv0 - b0.f, hv1 - b1.f);
                const uint q23 = pkbf(hv2 - b2.f, hv3 - b3.f);
                const int lg = (j * 16 + r16) >> 3;
                const int ie = r16 & 7;
                const int L0 = (lg << 4) | (g4 * 4);
                U.xf.H[w][mt][L0 + 0][ie] = (ushort)p01;
                U.xf.H[w][mt][L0 + 1][ie] = (ushort)(p01 >> 16);
                U.xf.H[w][mt][L0 + 2][ie] = (ushort)p23;
                U.xf.H[w][mt][L0 + 3][ie] = (ushort)(p23 >> 16);
                U.xf.L[w][mt][L0 + 0][ie] = (ushort)q01;
                U.xf.L[w][mt][L0 + 1][ie] = (ushort)(q01 >> 16);
                U.xf.L[w][mt][L0 + 2][ie] = (ushort)q23;
                U.xf.L[w][mt][L0 + 3][ie] = (ushort)(q23 >> 16);
            }
    }
    __syncthreads();

    // ---- phase B: g = h @ W1 (no relu), K=256 ----
    f32x4 gacc[2][2];
#pragma unroll
    for (int mt = 0; mt < 2; ++mt)
#pragma unroll
        for (int j = 0; j < 2; ++j) gacc[mt][j] = (f32x4){0.f, 0.f, 0.f, 0.f};

    for (int k8 = 0; k8 < 8; ++k8) {
        s16x8 bh0, bl0, bh1, bl1;
        loadB<SWZ>(W1H, W1L, W1, 8, nt0, k8, lane, bh0, bl0);
        loadB<SWZ>(W1H, W1L, W1, 8, nt1, k8, lane, bh1, bl1);
#pragma unroll
        for (int mt = 0; mt < 2; ++mt) {
            const s16x8 ah = *(const s16x8*)&U.xf.H[k8][mt][lane][0];
            const s16x8 aL = *(const s16x8*)&U.xf.L[k8][mt][lane][0];
            gacc[mt][0] = MFMA16(ah, bh0, gacc[mt][0]);
            gacc[mt][0] = MFMA16(aL, bh0, gacc[mt][0]);
            gacc[mt][0] = MFMA16(ah, bl0, gacc[mt][0]);
            gacc[mt][1] = MFMA16(ah, bh1, gacc[mt][1]);
            gacc[mt][1] = MFMA16(aL, bh1, gacc[mt][1]);
            gacc[mt][1] = MFMA16(ah, bl1, gacc[mt][1]);
        }
    }
#pragma unroll
    for (int mt = 0; mt < 2; ++mt)
#pragma unroll
        for (int j = 0; j < 2; ++j)
#pragma unroll
            for (int r = 0; r < 4; ++r)
                g_s[mt * 16 + g4 * 4 + r][(nt0 + j) * 16 + r16] = gacc[mt][j][r];
    __syncthreads();   // g_s ready; xf reads done (frag overlays xf next)

    const float wp0 = Wp[nt0 * 16 + r16], wp1 = Wp[nt1 * 16 + r16];

    // ---- phases C/D/E per 16-token sub-batch; M-tile n = 16 tokens of node n ----
    for (int sb = 0; sb < 2; ++sb) {
        f32x4 acc[NN][2];
#pragma unroll
        for (int n = 0; n < NN; ++n) {
            acc[n][0] = (f32x4){0.f, 0.f, 0.f, 0.f};
            acc[n][1] = (f32x4){0.f, 0.f, 0.f, 0.f};
        }

        for (int ks = 0; ks < 8; ++ks) {
            // build single-bf16 y1 fragments (one b128 per slot)
            for (int s = tid; s < NN * 64; s += 512) {
                const int n = s >> 6, l = s & 63;
                const int row = sb * 16 + (l & 15);
                const int k0 = ks * 32 + ((l >> 4) << 3);
                const f32x4 G0 = *(const f32x4*)&g_s[row][k0];
                const f32x4 G1 = *(const f32x4*)&g_s[row][k0 + 4];
                const f32x4 Sa = *(const f32x4*)&S_s[n][k0];
                const f32x4 Sb = *(const f32x4*)&S_s[n][k0 + 4];
                const float an = a_l[n];
                u32x4 uu;
                uu[0] = pkbf(fmaxf(fmaf(an, G0[0], Sa[0]), 0.f),
                             fmaxf(fmaf(an, G0[1], Sa[1]), 0.f));
                uu[1] = pkbf(fmaxf(fmaf(an, G0[2], Sa[2]), 0.f),
                             fmaxf(fmaf(an, G0[3], Sa[3]), 0.f));
                uu[2] = pkbf(fmaxf(fmaf(an, G1[0], Sb[0]), 0.f),
                             fmaxf(fmaf(an, G1[1], Sb[1]), 0.f));
                uu[3] = pkbf(fmaxf(fmaf(an, G1[2], Sb[2]), 0.f),
                             fmaxf(fmaf(an, G1[3], Sb[3]), 0.f));
                *(u32x4*)&U.frag[(size_t)s * 8] = uu;
            }
            __syncthreads();

            // consume: W2 single-bf16 (H only)
            s16x8 bh0, bh1;
            loadBH<SWZ>(W2H, W2, 8, nt0, ks, lane, bh0);
            loadBH<SWZ>(W2H, W2, 8, nt1, ks, lane, bh1);
#pragma unroll
            for (int n = 0; n < NN; ++n) {
                const s16x8 ah = *(const s16x8*)&U.frag[(n * 64 + lane) * 8];
                acc[n][0] = MFMA16(ah, bh0, acc[n][0]);
                acc[n][1] = MFMA16(ah, bh1, acc[n][1]);
            }
            __syncthreads();
        }

        // ---- phase E: y2 = relu(A @ z); score = y2 . Wp ----
        for (int e = 0; e < NE; ++e) {
            f32x4 z0 = (f32x4){0.f, 0.f, 0.f, 0.f}, z1 = (f32x4){0.f, 0.f, 0.f, 0.f};
#pragma unroll
            for (int n = 0; n < NN; ++n) {
                const float av = Ad_l[e * NN + n];
                if (av != 0.f) {   // uniform branch; A is very sparse (~3 nnz/row)
#pragma unroll
                    for (int r = 0; r < 4; ++r) {
                        z0[r] = fmaf(av, acc[n][0][r], z0[r]);
                        z1[r] = fmaf(av, acc[n][1][r], z1[r]);
                    }
                }
            }
            float v[4];
#pragma unroll
            for (int r = 0; r < 4; ++r)
                v[r] = fmaxf(z0[r], 0.f) * wp0 + fmaxf(z1[r], 0.f) * wp1;
#pragma unroll
            for (int off = 1; off < 16; off <<= 1)
#pragma unroll
                for (int r = 0; r < 4; ++r) v[r] += __shfl_xor(v[r], off, 64);
            if (r16 == 0)
#pragma unroll
                for (int r = 0; r < 4; ++r) part[w][g4 * 4 + r][e] = v[r];
        }
        __syncthreads();
        if (tid < 256) {
            const int t = tid >> 4, e = tid & 15;
            float s2 = 0.f;
#pragma unroll
            for (int q = 0; q < 8; ++q) s2 += part[q][t][e];
            out[(t0 + sb * 16 + t) * NE + e] = s2;
        }
        // next write to part is ≥16 barriers away (sb1's C loop); frag != part
    }
}

extern "C" void kernel_launch(void* const* d_in, const int* in_sizes, int n_in,
                              void* d_out, int out_size, void* d_ws, size_t ws_size,
                              hipStream_t stream) {
    const float* x   = (const float*)d_in[0];
    const float* X   = (const float*)d_in[1];
    const float* Wm  = (const float*)d_in[2];
    const float* Wst = (const float*)d_in[3];
    const float* Wc  = (const float*)d_in[4];
    const float* Wp  = (const float*)d_in[5];
    const float* adj = (const float*)d_in[6];
    float* out = (float*)d_out;
    float* ws  = (float*)d_ws;
    const float* W1 = Wc;
    const float* W2 = Wc + DG * DG;

    k_se1<<<NE, 512, 0, stream>>>(X, Wst, W1, ws);

    if (ws_size >= (size_t)WS_NEED) {
        k_se2<<<18 + 1536, 256, 0, stream>>>(adj, Wm, W1, W2, ws);
        k_main<true><<<NTOK / TB, 512, 0, stream>>>(x, Wm, W1, W2, Wp, ws, out);
    } else {
        k_se2<<<18, 256, 0, stream>>>(adj, Wm, W1, W2, ws);
        k_main<false><<<NTOK / TB, 512, 0, stream>>>(x, Wm, W1, W2, Wp, ws, out);
    }
}

// Round 6
// 107.817 us; speedup vs baseline: 6.5002x; 1.2814x over previous
//
#include <hip/hip_runtime.h>
#include <hip/hip_bf16.h>

typedef __attribute__((ext_vector_type(4))) float f32x4;
typedef __attribute__((ext_vector_type(8))) short s16x8;
typedef __attribute__((ext_vector_type(4))) uint u32x4;

#define MFMA16(a, b, c) __builtin_amdgcn_mfma_f32_16x16x32_bf16(a, b, c, 0, 0, 0)

#define DG 256
#define NE 16
#define NN 17
#define TB 32
#define NTOK 8192
#define PAD 276   // floats; 276/4 = 69 (odd) -> b128 row reads spread banks

// ws float offsets (small data)
#define WS_S    0        // S [17][256]
#define WS_A    4352     // a [17]
#define WS_AD   4376     // A dense [17*17]
#define WS_EW   8768     // exp@W1 [16][256]
// ws byte offsets (pre-swizzled bf16 hi/lo weight fragments)
#define FB_WMH  65536
#define FB_WML  589824
#define FB_W1H  1114112
#define FB_W1L  1245184
#define FB_W2H  1376256
#define FB_W2L  1507328
#define WS_NEED 1638400

// ---------- scalar RNE helpers (setup + fallback only) ----------
__device__ __forceinline__ ushort bf16h(float f) {
    union { float f; uint u; } c; c.f = f;
    return (ushort)((c.u + 0x7fffu + ((c.u >> 16) & 1u)) >> 16);  // RNE
}
__device__ __forceinline__ float bf16tof(ushort h) {
    union { uint u; float f; } c; c.u = (uint)h << 16;
    return c.f;
}
__device__ __forceinline__ void cvt_hilo(f32x4 a, f32x4 b, s16x8& hi, s16x8& lo) {
#pragma unroll
    for (int i = 0; i < 4; ++i) {
        const ushort h = bf16h(a[i]);
        hi[i] = (short)h;
        lo[i] = (short)bf16h(a[i] - bf16tof(h));
    }
#pragma unroll
    for (int i = 0; i < 4; ++i) {
        const ushort h = bf16h(b[i]);
        hi[4 + i] = (short)h;
        lo[4 + i] = (short)bf16h(b[i] - bf16tof(h));
    }
}

// ---------- fast packed converters (v_cvt_pk_bf16_f32) ----------
__device__ __forceinline__ uint pkbf(float a, float b) {
    __hip_bfloat162 t = __float22bfloat162_rn(make_float2(a, b));
    return *reinterpret_cast<uint*>(&t);
}
__device__ __forceinline__ void cvt_hilo_pk(f32x4 v0, f32x4 v1, s16x8& hi, s16x8& lo) {
    uint* hu = reinterpret_cast<uint*>(&hi);
    uint* lu = reinterpret_cast<uint*>(&lo);
    float a[8];
    *(f32x4*)a = v0; *(f32x4*)(a + 4) = v1;
#pragma unroll
    for (int i = 0; i < 4; ++i) {
        const uint h = pkbf(a[2 * i], a[2 * i + 1]);
        hu[i] = h;
        union { uint u; float f; } fa, fb;
        fa.u = h << 16; fb.u = h & 0xffff0000u;
        lu[i] = pkbf(a[2 * i] - fa.f, a[2 * i + 1] - fb.f);
    }
}

// B-operand fragment: b[i] = W[ks*32 + 8*(lane>>4) + i][nt*16 + (lane&15)]
template<bool SWZ>
__device__ __forceinline__ void loadB(const ushort* __restrict__ H,
                                      const ushort* __restrict__ L,
                                      const float* __restrict__ Wf,
                                      int KST, int nt, int ks, int lane,
                                      s16x8& bh, s16x8& bl) {
    if (SWZ) {
        const size_t off = ((size_t)(nt * KST + ks) * 64 + lane) * 8;
        bh = *(const s16x8*)(H + off);
        bl = *(const s16x8*)(L + off);
    } else {
        const int k0 = ks * 32 + ((lane >> 4) << 3);
        const int col = nt * 16 + (lane & 15);
        const float* p = Wf + (size_t)k0 * DG + col;
        f32x4 v0, v1;
#pragma unroll
        for (int i = 0; i < 4; ++i) v0[i] = p[(size_t)i * DG];
#pragma unroll
        for (int i = 0; i < 4; ++i) v1[i] = p[(size_t)(4 + i) * DG];
        cvt_hilo(v0, v1, bh, bl);
    }
}

template<bool SWZ>
__device__ __forceinline__ void loadBH(const ushort* __restrict__ H,
                                       const float* __restrict__ Wf,
                                       int KST, int nt, int ks, int lane,
                                       s16x8& bh) {
    if (SWZ) {
        bh = *(const s16x8*)(H + ((size_t)(nt * KST + ks) * 64 + lane) * 8);
    } else {
        const int k0 = ks * 32 + ((lane >> 4) << 3);
        const int col = nt * 16 + (lane & 15);
        const float* p = Wf + (size_t)k0 * DG + col;
#pragma unroll
        for (int i = 0; i < 8; ++i) bh[i] = (short)bf16h(p[(size_t)i * DG]);
    }
}

// ---------------- setup kernel 1: block e -> exp[e], ew[e] = exp[e] @ W1 ----------------
__global__ __launch_bounds__(512) void k_se1(const float* __restrict__ X,
                                             const float* __restrict__ Wst,
                                             const float* __restrict__ W1,
                                             float* __restrict__ ws) {
    const int e = blockIdx.x, tid = threadIdx.x;
    const int d = tid & 255, half = tid >> 8;
    __shared__ float xr[1024];
    __shared__ float part[2][256];
    __shared__ float er[256];

    *(float2*)&xr[tid * 2] = *(const float2*)&X[e * 1024 + tid * 2];
    __syncthreads();
    float acc = 0.f;
    const int k0 = half * 512;
    for (int k = 0; k < 512; ++k)
        acc = fmaf(xr[k0 + k], Wst[(size_t)(k0 + k) * DG + d], acc);
    part[half][d] = acc;
    __syncthreads();
    if (tid < 256) er[tid] = fmaxf(part[0][tid] + part[1][tid], 0.f);
    __syncthreads();
    float a2 = 0.f;
    const int m0 = half * 128;
    for (int m = 0; m < 128; ++m)
        a2 = fmaf(er[m0 + m], W1[(size_t)(m0 + m) * DG + d], a2);
    part[half][d] = a2;
    __syncthreads();
    if (tid < 256) ws[WS_EW + e * DG + tid] = part[0][tid] + part[1][tid];
}

// ---------------- setup kernel 2: blocks 0..17 adjacency/S; blocks 18+ swizzle ----------------
__global__ __launch_bounds__(256) void k_se2(const float* __restrict__ adj,
                                             const float* __restrict__ Wm,
                                             const float* __restrict__ W1,
                                             const float* __restrict__ W2,
                                             float* __restrict__ ws) {
    const int b = blockIdx.x, tid = threadIdx.x;
    if (b >= 18) {
        const int local = (b - 18) * 256 + tid;
        const float* W; ushort* H; ushort* L; int lo2, KST;
        char* base = (char*)ws;
        if (local < 262144)      { W = Wm; KST = 32; lo2 = local;          H = (ushort*)(base + FB_WMH); L = (ushort*)(base + FB_WML); }
        else if (local < 327680) { W = W1; KST = 8;  lo2 = local - 262144; H = (ushort*)(base + FB_W1H); L = (ushort*)(base + FB_W1L); }
        else                     { W = W2; KST = 8;  lo2 = local - 327680; H = (ushort*)(base + FB_W2H); L = (ushort*)(base + FB_W2L); }
        const int i = lo2 & 7, l = (lo2 >> 3) & 63, t = lo2 >> 9;
        const int ks = t % KST, nt = t / KST;
        const int k = ks * 32 + ((l >> 4) << 3) + i;
        const int col = nt * 16 + (l & 15);
        const float wv = W[(size_t)k * DG + col];
        const ushort h = bf16h(wv);
        H[lo2] = h;
        L[lo2] = bf16h(wv - bf16tof(h));
        return;
    }
    __shared__ float dinv[NN];
    __shared__ float row[NN];
    if (tid < NN) {
        float deg = 0.f;
        for (int m = 0; m < NN; ++m) deg += adj[tid * NN + m];
        dinv[tid] = 1.0f / sqrtf(deg);
    }
    __syncthreads();
    if (b < NN) {
        if (tid < NN) row[tid] = adj[b * NN + tid] * dinv[b] * dinv[tid];
        __syncthreads();
        float s = 0.f;
        for (int e = 0; e < NE; ++e) s = fmaf(row[e], ws[WS_EW + e * DG + tid], s);
        ws[WS_S + b * DG + tid] = s;
    } else {
        if (tid < NN) ws[WS_A + tid] = adj[tid * NN + NE] * dinv[tid] * dinv[NE];
        for (int i = tid; i < NN * NN; i += 256)
            ws[WS_AD + i] = adj[i] * dinv[i / NN] * dinv[i % NN];
    }
}

// ---------------- fused main kernel: 1024 thr, 16 waves (one col-tile each) ----------------
// __launch_bounds__(1024) single-arg: block size alone caps regs at 128/wave.
// (Round-4's (1024,4) second arg crushed the budget to 64 and spilled 92 MB.)
template<bool SWZ>
__global__ __launch_bounds__(1024) void k_main(
        const float* __restrict__ x,
        const float* __restrict__ Wm,
        const float* __restrict__ W1,
        const float* __restrict__ W2,
        const float* __restrict__ Wp,
        const float* __restrict__ ws,
        float* __restrict__ out) {
    const int tid = threadIdx.x;
    const int lane = tid & 63, w = tid >> 6;          // wave = col-tile 0..15
    const int r16 = lane & 15, g4 = lane >> 4;
    const size_t t0 = (size_t)blockIdx.x * TB;

    __shared__ float S_s[NN][PAD];                    // 18768 B
    __shared__ float g_s[TB][PAD];                    // 35328 B
    __shared__ alignas(16) union {
        struct { ushort H[8][2][64][8]; ushort L[8][2][64][8]; } xf;  // 32768 B
        ushort frag[2][NN * 64 * 8];                  // 34816 B (y1 dbuf)
    } U;
    __shared__ float part[16][16][NE];                // 16384 B
    __shared__ float a_l[NN];
    __shared__ float Ad_l[NN * NN];

    // staging map: thread -> (row, 8-float segment) of the x chunk
    const int xrow = tid >> 5;                        // 0..31
    const int xk0 = (tid & 31) * 8;                   // 0..248
    const int sks = xk0 >> 5;
    const int sl = (((xk0 >> 3) & 3) << 4) | (xrow & 15);
    const int smt = xrow >> 4;

    for (int j = tid; j < NN * DG; j += 1024) S_s[j >> 8][j & 255] = ws[WS_S + j];
    if (tid < NN) a_l[tid] = ws[WS_A + tid];
    for (int j = tid; j < NN * NN; j += 1024) Ad_l[j] = ws[WS_AD + j];

    const char* base = (const char*)ws;
    const ushort* WmH = (const ushort*)(base + FB_WMH);
    const ushort* WmL = (const ushort*)(base + FB_WML);
    const ushort* W1H = (const ushort*)(base + FB_W1H);
    const ushort* W1L = (const ushort*)(base + FB_W1L);
    const ushort* W2H = (const ushort*)(base + FB_W2H);

    // stage x chunk 0 (cooperative convert-once)
    {
        const float* px = x + (t0 + xrow) * 1024 + xk0;
        s16x8 hi, lo;
        cvt_hilo_pk(*(const f32x4*)px, *(const f32x4*)(px + 4), hi, lo);
        *(s16x8*)&U.xf.H[sks][smt][sl][0] = hi;
        *(s16x8*)&U.xf.L[sks][smt][sl][0] = lo;
    }
    __syncthreads();

    // ---- phase A: h = relu(x @ Wm), M=32 K=1024, 4 chunks of 256 ----
    f32x4 hacc[2];
    hacc[0] = (f32x4){0.f, 0.f, 0.f, 0.f};
    hacc[1] = (f32x4){0.f, 0.f, 0.f, 0.f};
    for (int c = 0; c < 4; ++c) {
        f32x4 xn0, xn1;
        if (c < 3) {   // issue next chunk's loads early; cvt+write after consume
            const float* px = x + (t0 + xrow) * 1024 + (c + 1) * 256 + xk0;
            xn0 = *(const f32x4*)px;
            xn1 = *(const f32x4*)(px + 4);
        }
        for (int k8 = 0; k8 < 8; ++k8) {
            s16x8 bh, bl;
            loadB<SWZ>(WmH, WmL, Wm, 32, w, c * 8 + k8, lane, bh, bl);
#pragma unroll
            for (int mt = 0; mt < 2; ++mt) {
                const s16x8 ah = *(const s16x8*)&U.xf.H[k8][mt][lane][0];
                const s16x8 aL = *(const s16x8*)&U.xf.L[k8][mt][lane][0];
                hacc[mt] = MFMA16(ah, bh, hacc[mt]);
                hacc[mt] = MFMA16(aL, bh, hacc[mt]);
                hacc[mt] = MFMA16(ah, bl, hacc[mt]);
            }
        }
        __syncthreads();
        if (c < 3) {
            s16x8 hi, lo;
            cvt_hilo_pk(xn0, xn1, hi, lo);
            *(s16x8*)&U.xf.H[sks][smt][sl][0] = hi;
            *(s16x8*)&U.xf.L[sks][smt][sl][0] = lo;
            __syncthreads();
        }
    }

    // write h (relu) directly as hi/lo MFMA A-fragments into xf (xf is dead now)
    {
        const int ksB = w >> 1;
        const int cb = (w * 2 + (r16 >> 3)) & 3;
        const int ie = r16 & 7;
#pragma unroll
        for (int mt = 0; mt < 2; ++mt) {
            const float hv0 = fmaxf(hacc[mt][0], 0.f), hv1 = fmaxf(hacc[mt][1], 0.f);
            const float hv2 = fmaxf(hacc[mt][2], 0.f), hv3 = fmaxf(hacc[mt][3], 0.f);
            const uint p01 = pkbf(hv0, hv1), p23 = pkbf(hv2, hv3);
            union { uint u; float f; } b0, b1, b2, b3;
            b0.u = p01 << 16; b1.u = p01 & 0xffff0000u;
            b2.u = p23 << 16; b3.u = p23 & 0xffff0000u;
            const uint q01 = pkbf(hv0 - b0.f, hv1 - b1.f);
            const uint q23 = pkbf(hv2 - b2.f, hv3 - b3.f);
            const int lr = cb * 16 + g4 * 4;
            U.xf.H[ksB][mt][lr + 0][ie] = (ushort)p01;
            U.xf.H[ksB][mt][lr + 1][ie] = (ushort)(p01 >> 16);
            U.xf.H[ksB][mt][lr + 2][ie] = (ushort)p23;
            U.xf.H[ksB][mt][lr + 3][ie] = (ushort)(p23 >> 16);
            U.xf.L[ksB][mt][lr + 0][ie] = (ushort)q01;
            U.xf.L[ksB][mt][lr + 1][ie] = (ushort)(q01 >> 16);
            U.xf.L[ksB][mt][lr + 2][ie] = (ushort)q23;
            U.xf.L[ksB][mt][lr + 3][ie] = (ushort)(q23 >> 16);
        }
    }
    __syncthreads();

    // ---- phase B: g = h @ W1 (no relu), K=256 ----
    f32x4 gacc[2];
    gacc[0] = (f32x4){0.f, 0.f, 0.f, 0.f};
    gacc[1] = (f32x4){0.f, 0.f, 0.f, 0.f};
    for (int k8 = 0; k8 < 8; ++k8) {
        s16x8 bh, bl;
        loadB<SWZ>(W1H, W1L, W1, 8, w, k8, lane, bh, bl);
#pragma unroll
        for (int mt = 0; mt < 2; ++mt) {
            const s16x8 ah = *(const s16x8*)&U.xf.H[k8][mt][lane][0];
            const s16x8 aL = *(const s16x8*)&U.xf.L[k8][mt][lane][0];
            gacc[mt] = MFMA16(ah, bh, gacc[mt]);
            gacc[mt] = MFMA16(aL, bh, gacc[mt]);
            gacc[mt] = MFMA16(ah, bl, gacc[mt]);
        }
    }
#pragma unroll
    for (int mt = 0; mt < 2; ++mt)
#pragma unroll
        for (int r = 0; r < 4; ++r)
            g_s[mt * 16 + g4 * 4 + r][w * 16 + r16] = gacc[mt][r];
    __syncthreads();   // g_s ready; xf reads done (frag overlays xf next)

    const float wp = Wp[w * 16 + r16];

    // ---- phases C/D/E per 16-token sub-batch; M-tile n = 16 tokens of node n ----
    for (int sb = 0; sb < 2; ++sb) {
        f32x4 acc[NN];
#pragma unroll
        for (int n = 0; n < NN; ++n) acc[n] = (f32x4){0.f, 0.f, 0.f, 0.f};

        for (int ks = 0; ks < 8; ++ks) {
            // prefetch W2 B-frag (single bf16) — global, independent of build
            s16x8 bh;
            loadBH<SWZ>(W2H, W2, 8, w, ks, lane, bh);

            // build single-bf16 y1 fragments into frag[(sb*8+ks)&1]
            ushort* fr = U.frag[(sb * 8 + ks) & 1];
            for (int s = tid; s < NN * 64; s += 1024) {
                const int n = s >> 6, l = s & 63;
                const int row = sb * 16 + (l & 15);
                const int k0 = ks * 32 + ((l >> 4) << 3);
                const f32x4 G0 = *(const f32x4*)&g_s[row][k0];
                const f32x4 G1 = *(const f32x4*)&g_s[row][k0 + 4];
                const f32x4 Sa = *(const f32x4*)&S_s[n][k0];
                const f32x4 Sb = *(const f32x4*)&S_s[n][k0 + 4];
                const float an = a_l[n];
                u32x4 uu;
                uu[0] = pkbf(fmaxf(fmaf(an, G0[0], Sa[0]), 0.f),
                             fmaxf(fmaf(an, G0[1], Sa[1]), 0.f));
                uu[1] = pkbf(fmaxf(fmaf(an, G0[2], Sa[2]), 0.f),
                             fmaxf(fmaf(an, G0[3], Sa[3]), 0.f));
                uu[2] = pkbf(fmaxf(fmaf(an, G1[0], Sb[0]), 0.f),
                             fmaxf(fmaf(an, G1[1], Sb[1]), 0.f));
                uu[3] = pkbf(fmaxf(fmaf(an, G1[2], Sb[2]), 0.f),
                             fmaxf(fmaf(an, G1[3], Sb[3]), 0.f));
                *(u32x4*)&fr[(size_t)s * 8] = uu;
            }
            __syncthreads();
            // dbuf: next ks writes the other buffer; its last readers finished
            // before the barrier above -> one barrier per ks suffices.

            const ushort* fb = U.frag[(sb * 8 + ks) & 1];
#pragma unroll
            for (int n = 0; n < NN; ++n) {
                const s16x8 ah = *(const s16x8*)&fb[(n * 64 + lane) * 8];
                acc[n] = MFMA16(ah, bh, acc[n]);
            }
        }

        // ---- phase E: y2 = relu(A @ z); score = y2 . Wp ----
        for (int e = 0; e < NE; ++e) {
            f32x4 z = (f32x4){0.f, 0.f, 0.f, 0.f};
#pragma unroll
            for (int n = 0; n < NN; ++n) {
                const float av = Ad_l[e * NN + n];
                if (av != 0.f) {   // uniform branch; A is very sparse
#pragma unroll
                    for (int r = 0; r < 4; ++r) z[r] = fmaf(av, acc[n][r], z[r]);
                }
            }
            float v[4];
#pragma unroll
            for (int r = 0; r < 4; ++r) v[r] = fmaxf(z[r], 0.f) * wp;
#pragma unroll
            for (int off = 1; off < 16; off <<= 1)
#pragma unroll
                for (int r = 0; r < 4; ++r) v[r] += __shfl_xor(v[r], off, 64);
            if (r16 == 0)
#pragma unroll
                for (int r = 0; r < 4; ++r) part[w][g4 * 4 + r][e] = v[r];
        }
        __syncthreads();
        if (tid < 256) {
            const int t = tid >> 4, e = tid & 15;
            float s2 = 0.f;
#pragma unroll
            for (int q = 0; q < 16; ++q) s2 += part[q][t][e];
            out[(t0 + sb * 16 + t) * NE + e] = s2;
        }
        // part's next write is behind sb1's per-ks barriers -> safe
    }
}

extern "C" void kernel_launch(void* const* d_in, const int* in_sizes, int n_in,
                              void* d_out, int out_size, void* d_ws, size_t ws_size,
                              hipStream_t stream) {
    const float* x   = (const float*)d_in[0];
    const float* X   = (const float*)d_in[1];
    const float* Wm  = (const float*)d_in[2];
    const float* Wst = (const float*)d_in[3];
    const float* Wc  = (const float*)d_in[4];
    const float* Wp  = (const float*)d_in[5];
    const float* adj = (const float*)d_in[6];
    float* out = (float*)d_out;
    float* ws  = (float*)d_ws;
    const float* W1 = Wc;
    const float* W2 = Wc + DG * DG;

    k_se1<<<NE, 512, 0, stream>>>(X, Wst, W1, ws);

    if (ws_size >= (size_t)WS_NEED) {
        k_se2<<<18 + 1536, 256, 0, stream>>>(adj, Wm, W1, W2, ws);
        k_main<true><<<NTOK / TB, 1024, 0, stream>>>(x, Wm, W1, W2, Wp, ws, out);
    } else {
        k_se2<<<18, 256, 0, stream>>>(adj, Wm, W1, W2, ws);
        k_main<false><<<NTOK / TB, 1024, 0, stream>>>(x, Wm, W1, W2, Wp, ws, out);
    }
}

// Round 7
// 102.812 us; speedup vs baseline: 6.8166x; 1.0487x over previous
//
#include <hip/hip_runtime.h>
#include <hip/hip_bf16.h>

typedef __attribute__((ext_vector_type(4))) float f32x4;
typedef __attribute__((ext_vector_type(8))) short s16x8;
typedef __attribute__((ext_vector_type(4))) uint u32x4;

#define MFMA16(a, b, c) __builtin_amdgcn_mfma_f32_16x16x32_bf16(a, b, c, 0, 0, 0)

#define DG 256
#define NE 16
#define NN 17
#define TB 32
#define NTOK 8192
#define PAD 276   // floats; row stride 1104 B (16B aligned)

// ws float offsets (small data)
#define WS_S    0        // S [17][256]
#define WS_A    4352     // a [17]
#define WS_AD   4376     // A dense [17*17]
#define WS_EW   8768     // exp@W1 [16][256]
// ws byte offsets (pre-swizzled bf16 weight fragments)
#define FB_WMH  65536
#define FB_WML  589824   // unused (Wm single-bf16)
#define FB_W1H  1114112
#define FB_W1L  1245184
#define FB_W2H  1376256
#define FB_W2L  1507328  // unused (W2 single-bf16)
#define WS_NEED 1638400

// ---------- scalar RNE helpers (setup + fallback only) ----------
__device__ __forceinline__ ushort bf16h(float f) {
    union { float f; uint u; } c; c.f = f;
    return (ushort)((c.u + 0x7fffu + ((c.u >> 16) & 1u)) >> 16);  // RNE
}
__device__ __forceinline__ float bf16tof(ushort h) {
    union { uint u; float f; } c; c.u = (uint)h << 16;
    return c.f;
}
__device__ __forceinline__ void cvt_hilo(f32x4 a, f32x4 b, s16x8& hi, s16x8& lo) {
#pragma unroll
    for (int i = 0; i < 4; ++i) {
        const ushort h = bf16h(a[i]);
        hi[i] = (short)h;
        lo[i] = (short)bf16h(a[i] - bf16tof(h));
    }
#pragma unroll
    for (int i = 0; i < 4; ++i) {
        const ushort h = bf16h(b[i]);
        hi[4 + i] = (short)h;
        lo[4 + i] = (short)bf16h(b[i] - bf16tof(h));
    }
}

// ---------- fast packed converters (v_cvt_pk_bf16_f32) ----------
__device__ __forceinline__ uint pkbf(float a, float b) {
    __hip_bfloat162 t = __float22bfloat162_rn(make_float2(a, b));
    return *reinterpret_cast<uint*>(&t);
}
__device__ __forceinline__ s16x8 cvt8_pk(f32x4 v0, f32x4 v1) {
    s16x8 r;
    uint* ru = reinterpret_cast<uint*>(&r);
    ru[0] = pkbf(v0[0], v0[1]);
    ru[1] = pkbf(v0[2], v0[3]);
    ru[2] = pkbf(v1[0], v1[1]);
    ru[3] = pkbf(v1[2], v1[3]);
    return r;
}
__device__ __forceinline__ void cvt_hilo_pk(f32x4 v0, f32x4 v1, s16x8& hi, s16x8& lo) {
    uint* hu = reinterpret_cast<uint*>(&hi);
    uint* lu = reinterpret_cast<uint*>(&lo);
    float a[8];
    *(f32x4*)a = v0; *(f32x4*)(a + 4) = v1;
#pragma unroll
    for (int i = 0; i < 4; ++i) {
        const uint h = pkbf(a[2 * i], a[2 * i + 1]);
        hu[i] = h;
        union { uint u; float f; } fa, fb;
        fa.u = h << 16; fb.u = h & 0xffff0000u;
        lu[i] = pkbf(a[2 * i] - fa.f, a[2 * i + 1] - fb.f);
    }
}

// B-operand fragment: b[i] = W[ks*32 + 8*(lane>>4) + i][nt*16 + (lane&15)]
template<bool SWZ>
__device__ __forceinline__ void loadB(const ushort* __restrict__ H,
                                      const ushort* __restrict__ L,
                                      const float* __restrict__ Wf,
                                      int KST, int nt, int ks, int lane,
                                      s16x8& bh, s16x8& bl) {
    if (SWZ) {
        const size_t off = ((size_t)(nt * KST + ks) * 64 + lane) * 8;
        bh = *(const s16x8*)(H + off);
        bl = *(const s16x8*)(L + off);
    } else {
        const int k0 = ks * 32 + ((lane >> 4) << 3);
        const int col = nt * 16 + (lane & 15);
        const float* p = Wf + (size_t)k0 * DG + col;
        f32x4 v0, v1;
#pragma unroll
        for (int i = 0; i < 4; ++i) v0[i] = p[(size_t)i * DG];
#pragma unroll
        for (int i = 0; i < 4; ++i) v1[i] = p[(size_t)(4 + i) * DG];
        cvt_hilo(v0, v1, bh, bl);
    }
}

template<bool SWZ>
__device__ __forceinline__ void loadBH(const ushort* __restrict__ H,
                                       const float* __restrict__ Wf,
                                       int KST, int nt, int ks, int lane,
                                       s16x8& bh) {
    if (SWZ) {
        bh = *(const s16x8*)(H + ((size_t)(nt * KST + ks) * 64 + lane) * 8);
    } else {
        const int k0 = ks * 32 + ((lane >> 4) << 3);
        const int col = nt * 16 + (lane & 15);
        const float* p = Wf + (size_t)k0 * DG + col;
#pragma unroll
        for (int i = 0; i < 8; ++i) bh[i] = (short)bf16h(p[(size_t)i * DG]);
    }
}

// ---------------- setup kernel 1: block e -> exp[e], ew[e] = exp[e] @ W1 ----------------
__global__ __launch_bounds__(512) void k_se1(const float* __restrict__ X,
                                             const float* __restrict__ Wst,
                                             const float* __restrict__ W1,
                                             float* __restrict__ ws) {
    const int e = blockIdx.x, tid = threadIdx.x;
    const int d = tid & 255, half = tid >> 8;
    __shared__ float xr[1024];
    __shared__ float part[2][256];
    __shared__ float er[256];

    *(float2*)&xr[tid * 2] = *(const float2*)&X[e * 1024 + tid * 2];
    __syncthreads();
    float acc = 0.f;
    const int k0 = half * 512;
    for (int k = 0; k < 512; ++k)
        acc = fmaf(xr[k0 + k], Wst[(size_t)(k0 + k) * DG + d], acc);
    part[half][d] = acc;
    __syncthreads();
    if (tid < 256) er[tid] = fmaxf(part[0][tid] + part[1][tid], 0.f);
    __syncthreads();
    float a2 = 0.f;
    const int m0 = half * 128;
    for (int m = 0; m < 128; ++m)
        a2 = fmaf(er[m0 + m], W1[(size_t)(m0 + m) * DG + d], a2);
    part[half][d] = a2;
    __syncthreads();
    if (tid < 256) ws[WS_EW + e * DG + tid] = part[0][tid] + part[1][tid];
}

// ---------------- setup kernel 2: blocks 0..17 adjacency/S; blocks 18+ swizzle (4 elem/thr) ----------------
__global__ __launch_bounds__(256) void k_se2(const float* __restrict__ adj,
                                             const float* __restrict__ Wm,
                                             const float* __restrict__ W1,
                                             const float* __restrict__ W2,
                                             float* __restrict__ ws) {
    const int b = blockIdx.x, tid = threadIdx.x;
    if (b >= 18) {
        char* base = (char*)ws;
        const int base4 = ((b - 18) * 256 + tid) * 4;
#pragma unroll
        for (int j = 0; j < 4; ++j) {
            const int local = base4 + j;
            const float* W; ushort* H; ushort* L; int lo2, KST; bool wantL;
            if (local < 262144)      { W = Wm; KST = 32; lo2 = local;          H = (ushort*)(base + FB_WMH); L = nullptr; wantL = false; }
            else if (local < 327680) { W = W1; KST = 8;  lo2 = local - 262144; H = (ushort*)(base + FB_W1H); L = (ushort*)(base + FB_W1L); wantL = true; }
            else                     { W = W2; KST = 8;  lo2 = local - 327680; H = (ushort*)(base + FB_W2H); L = nullptr; wantL = false; }
            const int i = lo2 & 7, l = (lo2 >> 3) & 63, t = lo2 >> 9;
            const int ks = t % KST, nt = t / KST;
            const int k = ks * 32 + ((l >> 4) << 3) + i;
            const int col = nt * 16 + (l & 15);
            const float wv = W[(size_t)k * DG + col];
            const ushort h = bf16h(wv);
            H[lo2] = h;
            if (wantL) L[lo2] = bf16h(wv - bf16tof(h));
        }
        return;
    }
    __shared__ float dinv[NN];
    __shared__ float row[NN];
    if (tid < NN) {
        float deg = 0.f;
        for (int m = 0; m < NN; ++m) deg += adj[tid * NN + m];
        dinv[tid] = 1.0f / sqrtf(deg);
    }
    __syncthreads();
    if (b < NN) {
        if (tid < NN) row[tid] = adj[b * NN + tid] * dinv[b] * dinv[tid];
        __syncthreads();
        float s = 0.f;
        for (int e = 0; e < NE; ++e) s = fmaf(row[e], ws[WS_EW + e * DG + tid], s);
        ws[WS_S + b * DG + tid] = s;
    } else {
        if (tid < NN) ws[WS_A + tid] = adj[tid * NN + NE] * dinv[tid] * dinv[NE];
        for (int i = tid; i < NN * NN; i += 256)
            ws[WS_AD + i] = adj[i] * dinv[i / NN] * dinv[i % NN];
    }
}

// ---------------- fused main kernel: 1024 thr, 16 waves (one col-tile each) ----------------
template<bool SWZ>
__global__ __launch_bounds__(1024) void k_main(
        const float* __restrict__ x,
        const float* __restrict__ Wm,
        const float* __restrict__ W1,
        const float* __restrict__ W2,
        const float* __restrict__ Wp,
        const float* __restrict__ ws,
        float* __restrict__ out) {
    const int tid = threadIdx.x;
    const int lane = tid & 63, w = tid >> 6;          // wave = col-tile 0..15
    const int r16 = lane & 15, g4 = lane >> 4;
    const size_t t0 = (size_t)blockIdx.x * TB;

    __shared__ float S_s[NN][PAD];                    // 18768 B
    __shared__ float g_s[TB][PAD];                    // 35328 B
    __shared__ alignas(16) union {
        ushort xs[2][8][2][64][8];                    // 32768 B (x frags, H-only, dbuf)
        struct { ushort H[8][2][64][8]; ushort L[8][2][64][8]; } hf;  // 32768 B
        ushort frag[2][NN * 64 * 8];                  // 34816 B (y1 dbuf)
    } U;
    __shared__ float part[16][16][20];                // 20480 B [t][e][w(+pad)]
    __shared__ float a_l[NN];
    __shared__ float Ad_l[NN * NN];

    // staging map: thread -> (row, 8-float segment) of the x chunk
    const int xrow = tid >> 5;                        // 0..31
    const int xk0 = (tid & 31) * 8;                   // 0..248
    const int sks = xk0 >> 5;
    const int sl = (((xk0 >> 3) & 3) << 4) | (xrow & 15);
    const int smt = xrow >> 4;

    for (int j = tid; j < NN * DG; j += 1024) S_s[j >> 8][j & 255] = ws[WS_S + j];
    if (tid < NN) a_l[tid] = ws[WS_A + tid];
    for (int j = tid; j < NN * NN; j += 1024) Ad_l[j] = ws[WS_AD + j];

    const char* base = (const char*)ws;
    const ushort* WmH = (const ushort*)(base + FB_WMH);
    const ushort* W1H = (const ushort*)(base + FB_W1H);
    const ushort* W1L = (const ushort*)(base + FB_W1L);
    const ushort* W2H = (const ushort*)(base + FB_W2H);

    // stage x chunk 0 (single bf16, convert-once)
    {
        const float* px = x + (t0 + xrow) * 1024 + xk0;
        *(s16x8*)&U.xs[0][sks][smt][sl][0] =
            cvt8_pk(*(const f32x4*)px, *(const f32x4*)(px + 4));
    }
    __syncthreads();

    // ---- phase A: h = relu(x @ Wm), x & Wm single-bf16, 4 chunks, x-dbuf, 1 barrier/chunk ----
    f32x4 hacc[2];
    hacc[0] = (f32x4){0.f, 0.f, 0.f, 0.f};
    hacc[1] = (f32x4){0.f, 0.f, 0.f, 0.f};
    for (int c = 0; c < 4; ++c) {
        f32x4 xn0, xn1;
        if (c < 3) {   // issue next chunk's loads early
            const float* px = x + (t0 + xrow) * 1024 + (c + 1) * 256 + xk0;
            xn0 = *(const f32x4*)px;
            xn1 = *(const f32x4*)(px + 4);
        }
        const ushort(*xb)[2][64][8] = U.xs[c & 1];
        for (int k8 = 0; k8 < 8; ++k8) {
            s16x8 bh;
            loadBH<SWZ>(WmH, Wm, 32, w, c * 8 + k8, lane, bh);
#pragma unroll
            for (int mt = 0; mt < 2; ++mt) {
                const s16x8 ah = *(const s16x8*)&xb[k8][mt][lane][0];
                hacc[mt] = MFMA16(ah, bh, hacc[mt]);
            }
        }
        if (c < 3) {   // write next chunk into the other buffer (no race: different half)
            *(s16x8*)&U.xs[(c + 1) & 1][sks][smt][sl][0] = cvt8_pk(xn0, xn1);
        }
        __syncthreads();
    }

    // write h (relu) directly as hi/lo MFMA A-fragments (x-bufs dead now)
    {
        const int ksB = w >> 1;
        const int cb = (w * 2 + (r16 >> 3)) & 3;
        const int ie = r16 & 7;
#pragma unroll
        for (int mt = 0; mt < 2; ++mt) {
            const float hv0 = fmaxf(hacc[mt][0], 0.f), hv1 = fmaxf(hacc[mt][1], 0.f);
            const float hv2 = fmaxf(hacc[mt][2], 0.f), hv3 = fmaxf(hacc[mt][3], 0.f);
            const uint p01 = pkbf(hv0, hv1), p23 = pkbf(hv2, hv3);
            union { uint u; float f; } b0, b1, b2, b3;
            b0.u = p01 << 16; b1.u = p01 & 0xffff0000u;
            b2.u = p23 << 16; b3.u = p23 & 0xffff0000u;
            const uint q01 = pkbf(hv0 - b0.f, hv1 - b1.f);
            const uint q23 = pkbf(hv2 - b2.f, hv3 - b3.f);
            const int lr = cb * 16 + g4 * 4;
            U.hf.H[ksB][mt][lr + 0][ie] = (ushort)p01;
            U.hf.H[ksB][mt][lr + 1][ie] = (ushort)(p01 >> 16);
            U.hf.H[ksB][mt][lr + 2][ie] = (ushort)p23;
            U.hf.H[ksB][mt][lr + 3][ie] = (ushort)(p23 >> 16);
            U.hf.L[ksB][mt][lr + 0][ie] = (ushort)q01;
            U.hf.L[ksB][mt][lr + 1][ie] = (ushort)(q01 >> 16);
            U.hf.L[ksB][mt][lr + 2][ie] = (ushort)q23;
            U.hf.L[ksB][mt][lr + 3][ie] = (ushort)(q23 >> 16);
        }
    }
    __syncthreads();

    // ---- phase B: g = h @ W1 (h hi/lo, W1 hi/lo), K=256 ----
    f32x4 gacc[2];
    gacc[0] = (f32x4){0.f, 0.f, 0.f, 0.f};
    gacc[1] = (f32x4){0.f, 0.f, 0.f, 0.f};
    for (int k8 = 0; k8 < 8; ++k8) {
        s16x8 bh, bl;
        loadB<SWZ>(W1H, W1L, W1, 8, w, k8, lane, bh, bl);
#pragma unroll
        for (int mt = 0; mt < 2; ++mt) {
            const s16x8 ah = *(const s16x8*)&U.hf.H[k8][mt][lane][0];
            const s16x8 aL = *(const s16x8*)&U.hf.L[k8][mt][lane][0];
            gacc[mt] = MFMA16(ah, bh, gacc[mt]);
            gacc[mt] = MFMA16(aL, bh, gacc[mt]);
            gacc[mt] = MFMA16(ah, bl, gacc[mt]);
        }
    }
#pragma unroll
    for (int mt = 0; mt < 2; ++mt)
#pragma unroll
        for (int r = 0; r < 4; ++r)
            g_s[mt * 16 + g4 * 4 + r][w * 16 + r16] = gacc[mt][r];
    __syncthreads();   // g_s ready; hf reads done (frag overlays next)

    const float wp = Wp[w * 16 + r16];

    // ---- phases C/D/E per 16-token sub-batch; M-tile n = 16 tokens of node n ----
    for (int sb = 0; sb < 2; ++sb) {
        f32x4 acc[NN];
#pragma unroll
        for (int n = 0; n < NN; ++n) acc[n] = (f32x4){0.f, 0.f, 0.f, 0.f};

        for (int ks = 0; ks < 8; ++ks) {
            // prefetch W2 B-frag (single bf16) — global, independent of build
            s16x8 bh;
            loadBH<SWZ>(W2H, W2, 8, w, ks, lane, bh);

            // build single-bf16 y1 fragments into frag[(sb*8+ks)&1] (unrolled 1088 slots)
            ushort* fr = U.frag[(sb * 8 + ks) & 1];
            auto build_slot = [&](int s) {
                const int n = s >> 6, l = s & 63;
                const int row = sb * 16 + (l & 15);
                const int k0 = ks * 32 + ((l >> 4) << 3);
                const f32x4 G0 = *(const f32x4*)&g_s[row][k0];
                const f32x4 G1 = *(const f32x4*)&g_s[row][k0 + 4];
                const f32x4 Sa = *(const f32x4*)&S_s[n][k0];
                const f32x4 Sb = *(const f32x4*)&S_s[n][k0 + 4];
                const float an = a_l[n];
                u32x4 uu;
                uu[0] = pkbf(fmaxf(fmaf(an, G0[0], Sa[0]), 0.f),
                             fmaxf(fmaf(an, G0[1], Sa[1]), 0.f));
                uu[1] = pkbf(fmaxf(fmaf(an, G0[2], Sa[2]), 0.f),
                             fmaxf(fmaf(an, G0[3], Sa[3]), 0.f));
                uu[2] = pkbf(fmaxf(fmaf(an, G1[0], Sb[0]), 0.f),
                             fmaxf(fmaf(an, G1[1], Sb[1]), 0.f));
                uu[3] = pkbf(fmaxf(fmaf(an, G1[2], Sb[2]), 0.f),
                             fmaxf(fmaf(an, G1[3], Sb[3]), 0.f));
                *(u32x4*)&fr[(size_t)s * 8] = uu;
            };
            build_slot(tid);
            if (tid < NN * 64 - 1024) build_slot(tid + 1024);
            __syncthreads();
            // dbuf: next ks writes the other buffer (its readers finished pre-barrier)

            const ushort* fb = U.frag[(sb * 8 + ks) & 1];
#pragma unroll
            for (int n = 0; n < NN; ++n) {
                const s16x8 ah = *(const s16x8*)&fb[(n * 64 + lane) * 8];
                acc[n] = MFMA16(ah, bh, acc[n]);
            }
        }

        // ---- phase E: y2 = relu(A @ z); score = y2 . Wp ; butterfly reduce over cols ----
#pragma unroll
        for (int q = 0; q < 4; ++q) {
            f32x4 v4[4];
#pragma unroll
            for (int e8 = 0; e8 < 4; ++e8) {
                const int e = q * 4 + e8;
                f32x4 z = (f32x4){0.f, 0.f, 0.f, 0.f};
#pragma unroll
                for (int n = 0; n < NN; ++n) {
                    const float av = Ad_l[e * NN + n];
                    if (av != 0.f) {
#pragma unroll
                        for (int r = 0; r < 4; ++r) z[r] = fmaf(av, acc[n][r], z[r]);
                    }
                }
#pragma unroll
                for (int r = 0; r < 4; ++r) v4[e8][r] = fmaxf(z[r], 0.f) * wp;
            }
            // stage 1 (mask 1): 4 -> 2 entries
            const bool b1 = (r16 & 1) != 0;
            f32x4 w2[2];
#pragma unroll
            for (int j = 0; j < 2; ++j)
#pragma unroll
                for (int r = 0; r < 4; ++r) {
                    const float keep = b1 ? v4[2 * j + 1][r] : v4[2 * j][r];
                    const float send = b1 ? v4[2 * j][r] : v4[2 * j + 1][r];
                    w2[j][r] = keep + __shfl_xor(send, 1, 64);
                }
            // stage 2 (mask 2): 2 -> 1 entry (e = q*4 + (r16&3))
            const bool b2 = (r16 & 2) != 0;
            f32x4 t1;
#pragma unroll
            for (int r = 0; r < 4; ++r) {
                const float keep = b2 ? w2[1][r] : w2[0][r];
                const float send = b2 ? w2[0][r] : w2[1][r];
                t1[r] = keep + __shfl_xor(send, 2, 64);
            }
            // finish column sum over remaining lane bits (4, 8)
#pragma unroll
            for (int r = 0; r < 4; ++r) t1[r] += __shfl_xor(t1[r], 4, 64);
#pragma unroll
            for (int r = 0; r < 4; ++r) t1[r] += __shfl_xor(t1[r], 8, 64);
            if ((r16 >> 2) == q) {   // writer lanes: e == r16
#pragma unroll
                for (int r = 0; r < 4; ++r) part[g4 * 4 + r][r16][w] = t1[r];
            }
        }
        __syncthreads();
        if (tid < 256) {
            const int t = tid >> 4, e = tid & 15;
            const f32x4 p0 = *(const f32x4*)&part[t][e][0];
            const f32x4 p1 = *(const f32x4*)&part[t][e][4];
            const f32x4 p2 = *(const f32x4*)&part[t][e][8];
            const f32x4 p3 = *(const f32x4*)&part[t][e][12];
            float s2 = 0.f;
#pragma unroll
            for (int r = 0; r < 4; ++r) s2 += p0[r] + p1[r] + p2[r] + p3[r];
            out[(t0 + sb * 16 + t) * NE + e] = s2;
        }
        // part's next write is behind sb1's per-ks barriers -> safe
    }
}

extern "C" void kernel_launch(void* const* d_in, const int* in_sizes, int n_in,
                              void* d_out, int out_size, void* d_ws, size_t ws_size,
                              hipStream_t stream) {
    const float* x   = (const float*)d_in[0];
    const float* X   = (const float*)d_in[1];
    const float* Wm  = (const float*)d_in[2];
    const float* Wst = (const float*)d_in[3];
    const float* Wc  = (const float*)d_in[4];
    const float* Wp  = (const float*)d_in[5];
    const float* adj = (const float*)d_in[6];
    float* out = (float*)d_out;
    float* ws  = (float*)d_ws;
    const float* W1 = Wc;
    const float* W2 = Wc + DG * DG;

    k_se1<<<NE, 512, 0, stream>>>(X, Wst, W1, ws);

    if (ws_size >= (size_t)WS_NEED) {
        k_se2<<<18 + 384, 256, 0, stream>>>(adj, Wm, W1, W2, ws);
        k_main<true><<<NTOK / TB, 1024, 0, stream>>>(x, Wm, W1, W2, Wp, ws, out);
    } else {
        k_se2<<<18, 256, 0, stream>>>(adj, Wm, W1, W2, ws);
        k_main<false><<<NTOK / TB, 1024, 0, stream>>>(x, Wm, W1, W2, Wp, ws, out);
    }
}